// Round 2
// baseline (4432.873 us; speedup 1.0000x reference)
//
#include <hip/hip_runtime.h>
#include <hip/hip_bf16.h>

typedef _Float16 f16_t;
typedef _Float16 f16x4 __attribute__((ext_vector_type(4)));
typedef _Float16 f16x8 __attribute__((ext_vector_type(8)));
typedef float f32x4 __attribute__((ext_vector_type(4)));

#define TILE_M 64
#define TILE_N 64
#define TILE_K 32

// C[M,N] = op(A[M,K] @ B) + bias, optional relu / rowscale / accumulate.
// BTRANS: B stored [N,K] (row-major), else [K,N]. fp32 in/out, f16 MFMA inside.
// Batch via blockIdx.z with element strides sA/sB/sC.
template<bool BTRANS, bool RELU, bool ACCUM, bool BIAS, bool ROWSCALE>
__global__ __launch_bounds__(256) void gemm_kernel(
    const float* __restrict__ A, const float* __restrict__ B, float* __restrict__ C,
    const float* __restrict__ bias, const float* __restrict__ rowscale, int rs_ld,
    int M, int N, int K, int lda, int ldb, int ldc,
    long long sA, long long sB, long long sC)
{
    __shared__ f16_t As[TILE_M][TILE_K + 8];
    __shared__ f16_t Bs[TILE_N][TILE_K + 8];   // stored [n][k]

    A += (long long)blockIdx.z * sA;
    B += (long long)blockIdx.z * sB;
    C += (long long)blockIdx.z * sC;

    const int m0 = blockIdx.y * TILE_M;
    const int n0 = blockIdx.x * TILE_N;
    const int t = threadIdx.x;
    const int wave = t >> 6, lane = t & 63;
    const int wr = (wave >> 1) * 32, wc = (wave & 1) * 32;
    const int lr = lane & 15, k8 = (lane >> 4) * 8;

    f32x4 acc00 = {}, acc01 = {}, acc10 = {}, acc11 = {};

    for (int k0 = 0; k0 < K; k0 += TILE_K) {
        // ---- stage A tile (64 rows x 32 k) ----
        {
            const int row = t >> 3, c4 = (t & 7) * 4;
            #pragma unroll
            for (int rr = 0; rr < 2; rr++) {
                float4 v = *reinterpret_cast<const float4*>(
                    &A[(long long)(m0 + row + rr * 32) * lda + (k0 + c4)]);
                f16x4 p = { (f16_t)v.x, (f16_t)v.y, (f16_t)v.z, (f16_t)v.w };
                *reinterpret_cast<f16x4*>(&As[row + rr * 32][c4]) = p;
            }
        }
        // ---- stage B tile as [n][k] ----
        if constexpr (BTRANS) {
            const int row = t >> 3, c4 = (t & 7) * 4;
            #pragma unroll
            for (int rr = 0; rr < 2; rr++) {
                float4 v = *reinterpret_cast<const float4*>(
                    &B[(long long)(n0 + row + rr * 32) * ldb + (k0 + c4)]);
                f16x4 p = { (f16_t)v.x, (f16_t)v.y, (f16_t)v.z, (f16_t)v.w };
                *reinterpret_cast<f16x4*>(&Bs[row + rr * 32][c4]) = p;
            }
        } else {
            const int kr = t >> 4, n4 = (t & 15) * 4;
            #pragma unroll
            for (int rr = 0; rr < 2; rr++) {
                float4 v = *reinterpret_cast<const float4*>(
                    &B[(long long)(k0 + kr + rr * 16) * ldb + (n0 + n4)]);
                const float* vf = reinterpret_cast<const float*>(&v);
                #pragma unroll
                for (int i = 0; i < 4; i++)
                    Bs[n4 + i][kr + rr * 16] = (f16_t)vf[i];
            }
        }
        __syncthreads();

        // fragments: lane holds A[row=lr][k8..k8+8), B[k8..k8+8)[col=lr]
        f16x8 a0 = *reinterpret_cast<const f16x8*>(&As[wr + lr][k8]);
        f16x8 a1 = *reinterpret_cast<const f16x8*>(&As[wr + 16 + lr][k8]);
        f16x8 b0 = *reinterpret_cast<const f16x8*>(&Bs[wc + lr][k8]);
        f16x8 b1 = *reinterpret_cast<const f16x8*>(&Bs[wc + 16 + lr][k8]);
        acc00 = __builtin_amdgcn_mfma_f32_16x16x32_f16(a0, b0, acc00, 0, 0, 0);
        acc01 = __builtin_amdgcn_mfma_f32_16x16x32_f16(a0, b1, acc01, 0, 0, 0);
        acc10 = __builtin_amdgcn_mfma_f32_16x16x32_f16(a1, b0, acc10, 0, 0, 0);
        acc11 = __builtin_amdgcn_mfma_f32_16x16x32_f16(a1, b1, acc11, 0, 0, 0);
        __syncthreads();
    }

    // epilogue: C/D layout col=lane&15, row=(lane>>4)*4+reg (m89-verified)
    const int er = (lane >> 4) * 4;
    const int ec = lane & 15;
    f32x4 accs[2][2] = { {acc00, acc01}, {acc10, acc11} };
    #pragma unroll
    for (int mi = 0; mi < 2; mi++) {
        #pragma unroll
        for (int ni = 0; ni < 2; ni++) {
            #pragma unroll
            for (int r = 0; r < 4; r++) {
                const int row = m0 + wr + mi * 16 + er + r;
                const int col = n0 + wc + ni * 16 + ec;
                float v = accs[mi][ni][r];
                if constexpr (BIAS) v += bias[col];
                if constexpr (RELU) v = fmaxf(v, 0.f);
                if constexpr (ROWSCALE) v *= rowscale[(long long)row * rs_ld];
                const long long ci = (long long)row * ldc + col;
                if constexpr (ACCUM) v += C[ci];
                C[ci] = v;
            }
        }
    }
}

// in-place row softmax over 2048 cols, with pre-scale
__global__ __launch_bounds__(256) void softmax_kernel(float* __restrict__ S,
                                                      long long zstride, float scale)
{
    float* row = S + (long long)blockIdx.z * zstride + (long long)blockIdx.x * 2048;
    const int t = threadIdx.x;
    float v[8];
    float mx = -1e30f;
    #pragma unroll
    for (int i = 0; i < 8; i++) {
        v[i] = row[t + i * 256] * scale;
        mx = fmaxf(mx, v[i]);
    }
    #pragma unroll
    for (int o = 32; o; o >>= 1) mx = fmaxf(mx, __shfl_xor(mx, o));
    __shared__ float wred[4];
    if ((t & 63) == 0) wred[t >> 6] = mx;
    __syncthreads();
    mx = fmaxf(fmaxf(wred[0], wred[1]), fmaxf(wred[2], wred[3]));
    __syncthreads();
    float s = 0.f;
    #pragma unroll
    for (int i = 0; i < 8; i++) { v[i] = __expf(v[i] - mx); s += v[i]; }
    #pragma unroll
    for (int o = 32; o; o >>= 1) s += __shfl_xor(s, o);
    if ((t & 63) == 0) wred[t >> 6] = s;
    __syncthreads();
    s = wred[0] + wred[1] + wred[2] + wred[3];
    const float inv = 1.f / s;
    #pragma unroll
    for (int i = 0; i < 8; i++) row[t + i * 256] = v[i] * inv;
}

// out = LN(in1 + in2) * gamma + beta (fp32). 1 wave/row, D=256.
__global__ __launch_bounds__(256) void ln_kernel(
    const float* __restrict__ in1, const float* __restrict__ in2,
    const float* __restrict__ gamma, const float* __restrict__ beta,
    float* __restrict__ out)
{
    const int wave = threadIdx.x >> 6, lane = threadIdx.x & 63;
    const long long row = (long long)blockIdx.x * 4 + wave;
    const long long base = row * 256 + lane * 4;
    float4 a = *reinterpret_cast<const float4*>(&in1[base]);
    float4 b = *reinterpret_cast<const float4*>(&in2[base]);
    float x[4] = { a.x + b.x, a.y + b.y, a.z + b.z, a.w + b.w };
    float s = x[0] + x[1] + x[2] + x[3];
    float s2 = x[0]*x[0] + x[1]*x[1] + x[2]*x[2] + x[3]*x[3];
    #pragma unroll
    for (int o = 32; o; o >>= 1) { s += __shfl_xor(s, o); s2 += __shfl_xor(s2, o); }
    const float mean = s * (1.f / 256.f);
    const float var = s2 * (1.f / 256.f) - mean * mean;
    const float rstd = rsqrtf(var + 1e-5f);
    float4 g = *reinterpret_cast<const float4*>(&gamma[lane * 4]);
    float4 bb = *reinterpret_cast<const float4*>(&beta[lane * 4]);
    const float* gf = reinterpret_cast<const float*>(&g);
    const float* bf = reinterpret_cast<const float*>(&bb);
    float y[4];
    #pragma unroll
    for (int i = 0; i < 4; i++) y[i] = (x[i] - mean) * rstd * gf[i] + bf[i];
    *reinterpret_cast<float4*>(&out[base]) = make_float4(y[0], y[1], y[2], y[3]);
}

// per-token: logits = x@Wg+bg -> softmax -> top2 -> comb row (dense, zeros elsewhere),
// atomicAdd full prob vector into counts[8]. 1 wave/token.
__global__ __launch_bounds__(256) void gating_kernel(
    const float* __restrict__ X, const float* __restrict__ Wg, const float* __restrict__ bg,
    float* __restrict__ comb, float* __restrict__ counts)
{
    const int wave = threadIdx.x >> 6, lane = threadIdx.x & 63;
    const int tok = blockIdx.x * 4 + wave;
    float accv[8] = {};
    const float4 xv = *reinterpret_cast<const float4*>(&X[(long long)tok * 256 + lane * 4]);
    const float* xf = reinterpret_cast<const float*>(&xv);
    #pragma unroll
    for (int i = 0; i < 4; i++) {
        const float xi = xf[i];
        const float* wrow = &Wg[(lane * 4 + i) * 8];
        #pragma unroll
        for (int e = 0; e < 8; e++) accv[e] += xi * wrow[e];
    }
    #pragma unroll
    for (int e = 0; e < 8; e++) {
        float s = accv[e];
        #pragma unroll
        for (int o = 32; o; o >>= 1) s += __shfl_xor(s, o);
        accv[e] = s;
    }
    if (lane == 0) {
        float p[8]; float mx = -1e30f;
        #pragma unroll
        for (int e = 0; e < 8; e++) { p[e] = accv[e] + bg[e]; mx = fmaxf(mx, p[e]); }
        float se = 0.f;
        #pragma unroll
        for (int e = 0; e < 8; e++) { p[e] = __expf(p[e] - mx); se += p[e]; }
        const float inv = 1.f / se;
        #pragma unroll
        for (int e = 0; e < 8; e++) { p[e] *= inv; atomicAdd(&counts[e], p[e]); }
        int i1 = 0;
        #pragma unroll
        for (int e = 1; e < 8; e++) if (p[e] > p[i1]) i1 = e;
        int i2 = (i1 == 0) ? 1 : 0;
        #pragma unroll
        for (int e = 0; e < 8; e++) if (e != i1 && p[e] > p[i2]) i2 = e;
        const float gs = 1.f / (p[i1] + p[i2]);
        float c[8] = {};
        c[i1] = p[i1] * gs; c[i2] = p[i2] * gs;
        float4* crow = reinterpret_cast<float4*>(&comb[(long long)tok * 8]);
        crow[0] = make_float4(c[0], c[1], c[2], c[3]);
        crow[1] = make_float4(c[4], c[5], c[6], c[7]);
    }
}

// aux = 0.01 * sum_pass E * sum_e frac_e * mean_probs_e ; both derive from counts.
__global__ void aux_kernel(const float* __restrict__ counts, float* __restrict__ out)
{
    if (threadIdx.x == 0) {
        float aux = 0.f;
        for (int pzz = 0; pzz < 2; pzz++) {
            const float* c = counts + pzz * 8;
            float tot = 0.f;
            for (int e = 0; e < 8; e++) tot += c[e];
            float s = 0.f;
            for (int e = 0; e < 8; e++) s += (c[e] / tot) * (c[e] * (1.f / 8192.f));
            aux += 8.f * s;
        }
        out[0] = 0.01f * aux;
    }
}

extern "C" void kernel_launch(void* const* d_in, const int* in_sizes, int n_in,
                              void* d_out, int out_size, void* d_ws, size_t ws_size,
                              hipStream_t stream)
{
    const float* Xc  = (const float*)d_in[0];
    const float* Xt  = (const float*)d_in[1];
    const float* Wq  = (const float*)d_in[2];
    const float* Wk  = (const float*)d_in[3];
    const float* Wv  = (const float*)d_in[4];
    const float* bq  = (const float*)d_in[5];
    const float* bk  = (const float*)d_in[6];
    const float* bv  = (const float*)d_in[7];
    const float* Wo  = (const float*)d_in[8];
    const float* bo  = (const float*)d_in[9];
    const float* Wg  = (const float*)d_in[10];
    const float* bg  = (const float*)d_in[11];
    const float* W1  = (const float*)d_in[12];
    const float* b1  = (const float*)d_in[13];
    const float* W2  = (const float*)d_in[14];
    const float* b2  = (const float*)d_in[15];
    const float* g_c1 = (const float*)d_in[16];
    const float* b_c1 = (const float*)d_in[17];
    const float* g_c2 = (const float*)d_in[18];
    const float* b_c2 = (const float*)d_in[19];
    const float* g_t1 = (const float*)d_in[20];
    const float* b_t1 = (const float*)d_in[21];
    const float* g_t2 = (const float*)d_in[22];
    const float* b_t2 = (const float*)d_in[23];

    const long long NTOK = 2097152;         // 8192 tokens * 256
    float* dout = (float*)d_out;            // fp32 outputs: xc | xt | aux
    float* xcout = dout;
    float* xtout = dout + NTOK;

    float* ws = (float*)d_ws;
    float* Q      = ws;                      // reused as P1 after attention
    float* Kp     = Q   + NTOK;
    float* Vp     = Kp  + NTOK;
    float* O      = Vp  + NTOK;
    float* X1     = O   + NTOK;
    float* F      = X1  + NTOK;
    float* H      = F   + NTOK;              // 8192 x 1024
    float* comb   = H   + 8388608;           // 8192 x 8
    float* counts = comb + 65536;            // 2 x 8
    float* Sb     = counts + 16;             // score scratch
    const long long S_PER = 2048LL * 2048LL;
    const size_t base_elems = (size_t)(Sb - ws);
    int nb = 1;
    if (ws_size >= (base_elems + 16 * (size_t)S_PER) * sizeof(float)) nb = 16;
    else if (ws_size >= (base_elems + 4 * (size_t)S_PER) * sizeof(float)) nb = 4;

    hipMemsetAsync(counts, 0, 16 * sizeof(float), stream);

    for (int pass = 0; pass < 2; pass++) {
        const float* xq  = pass ? Xt : Xc;
        const float* xkv = pass ? xcout : Xc;  // cross-att KV = finished context (fp32 in d_out)
        const float* g1  = pass ? g_t1 : g_c1;
        const float* be1 = pass ? b_t1 : b_c1;
        const float* g2  = pass ? g_t2 : g_c2;
        const float* be2 = pass ? b_t2 : b_c2;
        float* cnt = counts + pass * 8;
        float* oln = pass ? xtout : xcout;
        float* P1  = Q;                        // alias: Q dead after QK^T

        // Q/K/V projections: [8192,256] = X @ W + b
        gemm_kernel<false,false,false,true,false><<<dim3(4,128,1),256,0,stream>>>(
            xq,  Wq, Q,  bq, nullptr, 0, 8192, 256, 256, 256, 256, 256, 0, 0, 0);
        gemm_kernel<false,false,false,true,false><<<dim3(4,128,1),256,0,stream>>>(
            xkv, Wk, Kp, bk, nullptr, 0, 8192, 256, 256, 256, 256, 256, 0, 0, 0);
        gemm_kernel<false,false,false,true,false><<<dim3(4,128,1),256,0,stream>>>(
            xkv, Wv, Vp, bv, nullptr, 0, 8192, 256, 256, 256, 256, 256, 0, 0, 0);

        // attention per (b,h): z = b*4+h, base offset 64*z in [8192,256] viewed with ld 1024
        for (int z0 = 0; z0 < 16; z0 += nb) {
            gemm_kernel<true,false,false,false,false><<<dim3(32,32,nb),256,0,stream>>>(
                Q + 64 * z0, Kp + 64 * z0, Sb, nullptr, nullptr, 0,
                2048, 2048, 64, 1024, 1024, 2048, 64, 64, S_PER);
            softmax_kernel<<<dim3(2048,1,nb),256,0,stream>>>(Sb, S_PER, 0.125f);
            gemm_kernel<false,false,false,false,false><<<dim3(1,32,nb),256,0,stream>>>(
                Sb, Vp + 64 * z0, O + 64 * z0, nullptr, nullptr, 0,
                2048, 64, 2048, 2048, 1024, 1024, S_PER, 64, 64);
        }

        // output projection + LN1
        gemm_kernel<false,false,false,true,false><<<dim3(4,128,1),256,0,stream>>>(
            O, Wo, P1, bo, nullptr, 0, 8192, 256, 256, 256, 256, 256, 0, 0, 0);
        ln_kernel<<<2048,256,0,stream>>>(P1, xq, g1, be1, X1);

        // MoE (dense over experts, gated by comb)
        hipMemsetAsync(F, 0, NTOK * sizeof(float), stream);
        gating_kernel<<<2048,256,0,stream>>>(X1, Wg, bg, comb, cnt);
        for (int e = 0; e < 8; e++) {
            gemm_kernel<false,true,false,true,false><<<dim3(16,128,1),256,0,stream>>>(
                X1, W1 + (long long)e * 262144, H, b1 + e * 1024, nullptr, 0,
                8192, 1024, 256, 256, 1024, 1024, 0, 0, 0);
            gemm_kernel<false,false,true,true,true><<<dim3(4,128,1),256,0,stream>>>(
                H, W2 + (long long)e * 262144, F, b2 + e * 256, comb + e, 8,
                8192, 256, 1024, 1024, 256, 256, 0, 0, 0);
        }
        // LN2 -> fp32 output region (context region doubles as pass-1 KV)
        ln_kernel<<<2048,256,0,stream>>>(F, X1, g2, be2, oln);
    }

    aux_kernel<<<1,64,0,stream>>>(counts, dout + 2 * NTOK);
}

// Round 3
// 1643.405 us; speedup vs baseline: 2.6974x; 2.6974x over previous
//
#include <hip/hip_runtime.h>
#include <hip/hip_bf16.h>

typedef _Float16 f16_t;
typedef _Float16 f16x4 __attribute__((ext_vector_type(4)));
typedef _Float16 f16x8 __attribute__((ext_vector_type(8)));
typedef float f32x4 __attribute__((ext_vector_type(4)));

#define TILE_M 64
#define TILE_N 64
#define TILE_K 32

// ---------------- generic GEMM (projections + attention) ----------------
// C[M,N] = A[M,K] @ B (+bias). BTRANS: B stored [N,K]. fp32 in/out, f16 MFMA.
template<bool BTRANS, bool BIAS>
__global__ __launch_bounds__(256) void gemm_kernel(
    const float* __restrict__ A, const float* __restrict__ B, float* __restrict__ C,
    const float* __restrict__ bias,
    int M, int N, int K, int lda, int ldb, int ldc,
    long long sA, long long sB, long long sC)
{
    __shared__ f16_t As[TILE_M][TILE_K + 8];
    __shared__ f16_t Bs[TILE_N][TILE_K + 8];   // stored [n][k]

    A += (long long)blockIdx.z * sA;
    B += (long long)blockIdx.z * sB;
    C += (long long)blockIdx.z * sC;

    const int m0 = blockIdx.y * TILE_M;
    const int n0 = blockIdx.x * TILE_N;
    const int t = threadIdx.x;
    const int wave = t >> 6, lane = t & 63;
    const int wr = (wave >> 1) * 32, wc = (wave & 1) * 32;
    const int lr = lane & 15, k8 = (lane >> 4) * 8;

    f32x4 acc00 = {}, acc01 = {}, acc10 = {}, acc11 = {};

    for (int k0 = 0; k0 < K; k0 += TILE_K) {
        {
            const int row = t >> 3, c4 = (t & 7) * 4;
            #pragma unroll
            for (int rr = 0; rr < 2; rr++) {
                float4 v = *reinterpret_cast<const float4*>(
                    &A[(long long)(m0 + row + rr * 32) * lda + (k0 + c4)]);
                f16x4 p = { (f16_t)v.x, (f16_t)v.y, (f16_t)v.z, (f16_t)v.w };
                *reinterpret_cast<f16x4*>(&As[row + rr * 32][c4]) = p;
            }
        }
        if constexpr (BTRANS) {
            const int row = t >> 3, c4 = (t & 7) * 4;
            #pragma unroll
            for (int rr = 0; rr < 2; rr++) {
                float4 v = *reinterpret_cast<const float4*>(
                    &B[(long long)(n0 + row + rr * 32) * ldb + (k0 + c4)]);
                f16x4 p = { (f16_t)v.x, (f16_t)v.y, (f16_t)v.z, (f16_t)v.w };
                *reinterpret_cast<f16x4*>(&Bs[row + rr * 32][c4]) = p;
            }
        } else {
            const int kr = t >> 4, n4 = (t & 15) * 4;
            #pragma unroll
            for (int rr = 0; rr < 2; rr++) {
                float4 v = *reinterpret_cast<const float4*>(
                    &B[(long long)(k0 + kr + rr * 16) * ldb + (n0 + n4)]);
                const float* vf = reinterpret_cast<const float*>(&v);
                #pragma unroll
                for (int i = 0; i < 4; i++)
                    Bs[n4 + i][kr + rr * 16] = (f16_t)vf[i];
            }
        }
        __syncthreads();

        f16x8 a0 = *reinterpret_cast<const f16x8*>(&As[wr + lr][k8]);
        f16x8 a1 = *reinterpret_cast<const f16x8*>(&As[wr + 16 + lr][k8]);
        f16x8 b0 = *reinterpret_cast<const f16x8*>(&Bs[wc + lr][k8]);
        f16x8 b1 = *reinterpret_cast<const f16x8*>(&Bs[wc + 16 + lr][k8]);
        acc00 = __builtin_amdgcn_mfma_f32_16x16x32_f16(a0, b0, acc00, 0, 0, 0);
        acc01 = __builtin_amdgcn_mfma_f32_16x16x32_f16(a0, b1, acc01, 0, 0, 0);
        acc10 = __builtin_amdgcn_mfma_f32_16x16x32_f16(a1, b0, acc10, 0, 0, 0);
        acc11 = __builtin_amdgcn_mfma_f32_16x16x32_f16(a1, b1, acc11, 0, 0, 0);
        __syncthreads();
    }

    const int er = (lane >> 4) * 4;
    const int ec = lane & 15;
    f32x4 accs[2][2] = { {acc00, acc01}, {acc10, acc11} };
    #pragma unroll
    for (int mi = 0; mi < 2; mi++) {
        #pragma unroll
        for (int ni = 0; ni < 2; ni++) {
            #pragma unroll
            for (int r = 0; r < 4; r++) {
                const int row = m0 + wr + mi * 16 + er + r;
                const int col = n0 + wc + ni * 16 + ec;
                float v = accs[mi][ni][r];
                if constexpr (BIAS) v += bias[col];
                C[(long long)row * ldc + col] = v;
            }
        }
    }
}

// ---------------- MoE expert GEMM (slot-compacted, expert from block row) ----
// GATHER: A row = Xsrc[tok_of_slot[slot]] (lda), else A row = A[slot].
template<bool GATHER, bool RELU>
__global__ __launch_bounds__(256) void moe_gemm_kernel(
    const float* __restrict__ A, const int* __restrict__ tok_of_slot,
    const float* __restrict__ W, const float* __restrict__ bias,
    float* __restrict__ C, const int* __restrict__ ebase,
    int N, int K, int lda, int ldb, int ldc, int wstride, int bstride)
{
    const int m0 = blockIdx.y * TILE_M;
    if (m0 >= ebase[8]) return;
    int e = 0;
    #pragma unroll
    for (int i = 1; i < 8; i++) if (m0 >= ebase[i]) e = i;
    const float* __restrict__ B  = W + (long long)e * wstride;
    const float* __restrict__ bs = bias + e * bstride;

    __shared__ f16_t As[TILE_M][TILE_K + 8];
    __shared__ f16_t Bs[TILE_N][TILE_K + 8];

    const int n0 = blockIdx.x * TILE_N;
    const int t = threadIdx.x;
    const int wave = t >> 6, lane = t & 63;
    const int wr = (wave >> 1) * 32, wc = (wave & 1) * 32;
    const int lr = lane & 15, k8 = (lane >> 4) * 8;

    // hoist gather row pointers
    const int arow = t >> 3, c4 = (t & 7) * 4;
    const float* arp0;
    const float* arp1;
    if constexpr (GATHER) {
        arp0 = A + (long long)tok_of_slot[m0 + arow] * lda;
        arp1 = A + (long long)tok_of_slot[m0 + arow + 32] * lda;
    } else {
        arp0 = A + (long long)(m0 + arow) * lda;
        arp1 = A + (long long)(m0 + arow + 32) * lda;
    }

    f32x4 acc00 = {}, acc01 = {}, acc10 = {}, acc11 = {};

    for (int k0 = 0; k0 < K; k0 += TILE_K) {
        {
            float4 v0 = *reinterpret_cast<const float4*>(arp0 + k0 + c4);
            float4 v1 = *reinterpret_cast<const float4*>(arp1 + k0 + c4);
            f16x4 p0 = { (f16_t)v0.x, (f16_t)v0.y, (f16_t)v0.z, (f16_t)v0.w };
            f16x4 p1 = { (f16_t)v1.x, (f16_t)v1.y, (f16_t)v1.z, (f16_t)v1.w };
            *reinterpret_cast<f16x4*>(&As[arow][c4]) = p0;
            *reinterpret_cast<f16x4*>(&As[arow + 32][c4]) = p1;
        }
        {
            const int kr = t >> 4, n4 = (t & 15) * 4;
            #pragma unroll
            for (int rr = 0; rr < 2; rr++) {
                float4 v = *reinterpret_cast<const float4*>(
                    &B[(long long)(k0 + kr + rr * 16) * ldb + (n0 + n4)]);
                const float* vf = reinterpret_cast<const float*>(&v);
                #pragma unroll
                for (int i = 0; i < 4; i++)
                    Bs[n4 + i][kr + rr * 16] = (f16_t)vf[i];
            }
        }
        __syncthreads();

        f16x8 a0 = *reinterpret_cast<const f16x8*>(&As[wr + lr][k8]);
        f16x8 a1 = *reinterpret_cast<const f16x8*>(&As[wr + 16 + lr][k8]);
        f16x8 b0 = *reinterpret_cast<const f16x8*>(&Bs[wc + lr][k8]);
        f16x8 b1 = *reinterpret_cast<const f16x8*>(&Bs[wc + 16 + lr][k8]);
        acc00 = __builtin_amdgcn_mfma_f32_16x16x32_f16(a0, b0, acc00, 0, 0, 0);
        acc01 = __builtin_amdgcn_mfma_f32_16x16x32_f16(a0, b1, acc01, 0, 0, 0);
        acc10 = __builtin_amdgcn_mfma_f32_16x16x32_f16(a1, b0, acc10, 0, 0, 0);
        acc11 = __builtin_amdgcn_mfma_f32_16x16x32_f16(a1, b1, acc11, 0, 0, 0);
        __syncthreads();
    }

    const int er = (lane >> 4) * 4;
    const int ec = lane & 15;
    f32x4 accs[2][2] = { {acc00, acc01}, {acc10, acc11} };
    #pragma unroll
    for (int mi = 0; mi < 2; mi++) {
        #pragma unroll
        for (int ni = 0; ni < 2; ni++) {
            #pragma unroll
            for (int r = 0; r < 4; r++) {
                const int row = m0 + wr + mi * 16 + er + r;
                const int col = n0 + wc + ni * 16 + ec;
                float v = accs[mi][ni][r] + bs[col];
                if constexpr (RELU) v = fmaxf(v, 0.f);
                C[(long long)row * ldc + col] = v;
            }
        }
    }
}

// ---------------- softmax over 2048 cols ----------------
__global__ __launch_bounds__(256) void softmax_kernel(float* __restrict__ S,
                                                      long long zstride, float scale)
{
    float* row = S + (long long)blockIdx.z * zstride + (long long)blockIdx.x * 2048;
    const int t = threadIdx.x;
    float v[8];
    float mx = -1e30f;
    #pragma unroll
    for (int i = 0; i < 8; i++) {
        v[i] = row[t + i * 256] * scale;
        mx = fmaxf(mx, v[i]);
    }
    #pragma unroll
    for (int o = 32; o; o >>= 1) mx = fmaxf(mx, __shfl_xor(mx, o));
    __shared__ float wred[4];
    if ((t & 63) == 0) wred[t >> 6] = mx;
    __syncthreads();
    mx = fmaxf(fmaxf(wred[0], wred[1]), fmaxf(wred[2], wred[3]));
    __syncthreads();
    float s = 0.f;
    #pragma unroll
    for (int i = 0; i < 8; i++) { v[i] = __expf(v[i] - mx); s += v[i]; }
    #pragma unroll
    for (int o = 32; o; o >>= 1) s += __shfl_xor(s, o);
    if ((t & 63) == 0) wred[t >> 6] = s;
    __syncthreads();
    s = wred[0] + wred[1] + wred[2] + wred[3];
    const float inv = 1.f / s;
    #pragma unroll
    for (int i = 0; i < 8; i++) row[t + i * 256] = v[i] * inv;
}

// ---------------- LN(in1+in2)*g+b, 1 wave/row, D=256 ----------------
__global__ __launch_bounds__(256) void ln_kernel(
    const float* __restrict__ in1, const float* __restrict__ in2,
    const float* __restrict__ gamma, const float* __restrict__ beta,
    float* __restrict__ out)
{
    const int wave = threadIdx.x >> 6, lane = threadIdx.x & 63;
    const long long row = (long long)blockIdx.x * 4 + wave;
    const long long base = row * 256 + lane * 4;
    float4 a = *reinterpret_cast<const float4*>(&in1[base]);
    float4 b = *reinterpret_cast<const float4*>(&in2[base]);
    float x[4] = { a.x + b.x, a.y + b.y, a.z + b.z, a.w + b.w };
    float s = x[0] + x[1] + x[2] + x[3];
    float s2 = x[0]*x[0] + x[1]*x[1] + x[2]*x[2] + x[3]*x[3];
    #pragma unroll
    for (int o = 32; o; o >>= 1) { s += __shfl_xor(s, o); s2 += __shfl_xor(s2, o); }
    const float mean = s * (1.f / 256.f);
    const float var = s2 * (1.f / 256.f) - mean * mean;
    const float rstd = rsqrtf(var + 1e-5f);
    float4 g = *reinterpret_cast<const float4*>(&gamma[lane * 4]);
    float4 bb = *reinterpret_cast<const float4*>(&beta[lane * 4]);
    const float* gf = reinterpret_cast<const float*>(&g);
    const float* bf = reinterpret_cast<const float*>(&bb);
    float y[4];
    #pragma unroll
    for (int i = 0; i < 4; i++) y[i] = (x[i] - mean) * rstd * gf[i] + bf[i];
    *reinterpret_cast<float4*>(&out[base]) = make_float4(y[0], y[1], y[2], y[3]);
}

// ---------------- gating: 1 thread/token, hierarchical counting ----------------
__global__ __launch_bounds__(256) void gating_kernel(
    const float* __restrict__ X, const float* __restrict__ Wg, const float* __restrict__ bg,
    int* __restrict__ gcount, float* __restrict__ counts,
    int* __restrict__ pos_of_tok, int* __restrict__ exp_of_tok,
    float* __restrict__ gate_of_tok)
{
    __shared__ float WgL[2048];
    __shared__ float cpart[8];
    __shared__ int lcnt[8];
    __shared__ int lbase[8];
    const int t = threadIdx.x;
    for (int i = t; i < 2048; i += 256) WgL[i] = Wg[i];
    if (t < 8) { cpart[t] = 0.f; lcnt[t] = 0; }
    __syncthreads();

    const int tok = blockIdx.x * 256 + t;
    const float* xr = X + (long long)tok * 256;
    float acc[8] = {};
    for (int k = 0; k < 256; k += 4) {
        float4 xv = *reinterpret_cast<const float4*>(xr + k);
        const float* xf = reinterpret_cast<const float*>(&xv);
        #pragma unroll
        for (int i = 0; i < 4; i++) {
            const float xi = xf[i];
            const float* wrow = &WgL[(k + i) * 8];
            #pragma unroll
            for (int e = 0; e < 8; e++) acc[e] += xi * wrow[e];
        }
    }
    float p[8]; float mx = -1e30f;
    #pragma unroll
    for (int e = 0; e < 8; e++) { p[e] = acc[e] + bg[e]; mx = fmaxf(mx, p[e]); }
    float se = 0.f;
    #pragma unroll
    for (int e = 0; e < 8; e++) { p[e] = __expf(p[e] - mx); se += p[e]; }
    const float inv = 1.f / se;
    #pragma unroll
    for (int e = 0; e < 8; e++) { p[e] *= inv; atomicAdd(&cpart[e], p[e]); }

    int i1 = 0;
    #pragma unroll
    for (int e = 1; e < 8; e++) if (p[e] > p[i1]) i1 = e;
    int i2 = (i1 == 0) ? 1 : 0;
    #pragma unroll
    for (int e = 0; e < 8; e++) if (e != i1 && p[e] > p[i2]) i2 = e;
    const float gs = 1.f / (p[i1] + p[i2]);

    const int p1 = atomicAdd(&lcnt[i1], 1);
    const int p2 = atomicAdd(&lcnt[i2], 1);
    __syncthreads();
    if (t < 8) {
        lbase[t] = atomicAdd(&gcount[t], lcnt[t]);
        atomicAdd(&counts[t], cpart[t]);
    }
    __syncthreads();
    pos_of_tok[2 * tok]     = lbase[i1] + p1;
    pos_of_tok[2 * tok + 1] = lbase[i2] + p2;
    exp_of_tok[2 * tok]     = i1;
    exp_of_tok[2 * tok + 1] = i2;
    gate_of_tok[2 * tok]     = p[i1] * gs;
    gate_of_tok[2 * tok + 1] = p[i2] * gs;
}

// 64-aligned prefix bases
__global__ void finalize_kernel(const int* __restrict__ gcount, int* __restrict__ ebase)
{
    if (threadIdx.x == 0) {
        int b = 0;
        for (int e = 0; e < 8; e++) { ebase[e] = b; b += (gcount[e] + 63) & ~63; }
        ebase[8] = b;
    }
}

// slot -> token map
__global__ __launch_bounds__(256) void scatter_kernel(
    const int* __restrict__ pos_of_tok, const int* __restrict__ exp_of_tok,
    const int* __restrict__ ebase, int* __restrict__ tok_of_slot)
{
    const int i = blockIdx.x * 256 + threadIdx.x;   // 0..16383
    const int e = exp_of_tok[i];
    tok_of_slot[ebase[e] + pos_of_tok[i]] = i >> 1;
}

// out = LN(gv1*Ys[s1] + gv2*Ys[s2] + X1) ; Ys rows already include b2.
__global__ __launch_bounds__(256) void moe_combine_ln_kernel(
    const float* __restrict__ Ys, const float* __restrict__ X1,
    const int* __restrict__ pos_of_tok, const int* __restrict__ exp_of_tok,
    const float* __restrict__ gate_of_tok, const int* __restrict__ ebase,
    const float* __restrict__ gamma, const float* __restrict__ beta,
    float* __restrict__ out)
{
    const int wave = threadIdx.x >> 6, lane = threadIdx.x & 63;
    const long long tok = (long long)blockIdx.x * 4 + wave;
    const int e1 = exp_of_tok[2 * tok], e2 = exp_of_tok[2 * tok + 1];
    const long long s1 = ebase[e1] + pos_of_tok[2 * tok];
    const long long s2 = ebase[e2] + pos_of_tok[2 * tok + 1];
    const float gv1 = gate_of_tok[2 * tok], gv2 = gate_of_tok[2 * tok + 1];
    const long long base = tok * 256 + lane * 4;
    float4 y1 = *reinterpret_cast<const float4*>(&Ys[s1 * 256 + lane * 4]);
    float4 y2 = *reinterpret_cast<const float4*>(&Ys[s2 * 256 + lane * 4]);
    float4 xv = *reinterpret_cast<const float4*>(&X1[base]);
    float x[4] = { gv1 * y1.x + gv2 * y2.x + xv.x,
                   gv1 * y1.y + gv2 * y2.y + xv.y,
                   gv1 * y1.z + gv2 * y2.z + xv.z,
                   gv1 * y1.w + gv2 * y2.w + xv.w };
    float s = x[0] + x[1] + x[2] + x[3];
    float s2v = x[0]*x[0] + x[1]*x[1] + x[2]*x[2] + x[3]*x[3];
    #pragma unroll
    for (int o = 32; o; o >>= 1) { s += __shfl_xor(s, o); s2v += __shfl_xor(s2v, o); }
    const float mean = s * (1.f / 256.f);
    const float var = s2v * (1.f / 256.f) - mean * mean;
    const float rstd = rsqrtf(var + 1e-5f);
    float4 g = *reinterpret_cast<const float4*>(&gamma[lane * 4]);
    float4 bb = *reinterpret_cast<const float4*>(&beta[lane * 4]);
    const float* gf = reinterpret_cast<const float*>(&g);
    const float* bf = reinterpret_cast<const float*>(&bb);
    float y[4];
    #pragma unroll
    for (int i = 0; i < 4; i++) y[i] = (x[i] - mean) * rstd * gf[i] + bf[i];
    *reinterpret_cast<float4*>(&out[base]) = make_float4(y[0], y[1], y[2], y[3]);
}

// aux from counts
__global__ void aux_kernel(const float* __restrict__ counts, float* __restrict__ out)
{
    if (threadIdx.x == 0) {
        float aux = 0.f;
        for (int pzz = 0; pzz < 2; pzz++) {
            const float* c = counts + pzz * 8;
            float tot = 0.f;
            for (int e = 0; e < 8; e++) tot += c[e];
            float s = 0.f;
            for (int e = 0; e < 8; e++) s += (c[e] / tot) * (c[e] * (1.f / 8192.f));
            aux += 8.f * s;
        }
        out[0] = 0.01f * aux;
    }
}

extern "C" void kernel_launch(void* const* d_in, const int* in_sizes, int n_in,
                              void* d_out, int out_size, void* d_ws, size_t ws_size,
                              hipStream_t stream)
{
    const float* Xc  = (const float*)d_in[0];
    const float* Xt  = (const float*)d_in[1];
    const float* Wq  = (const float*)d_in[2];
    const float* Wk  = (const float*)d_in[3];
    const float* Wv  = (const float*)d_in[4];
    const float* bq  = (const float*)d_in[5];
    const float* bk  = (const float*)d_in[6];
    const float* bv  = (const float*)d_in[7];
    const float* Wo  = (const float*)d_in[8];
    const float* bo  = (const float*)d_in[9];
    const float* Wg  = (const float*)d_in[10];
    const float* bg  = (const float*)d_in[11];
    const float* W1  = (const float*)d_in[12];
    const float* b1  = (const float*)d_in[13];
    const float* W2  = (const float*)d_in[14];
    const float* b2  = (const float*)d_in[15];
    const float* g_c1 = (const float*)d_in[16];
    const float* b_c1 = (const float*)d_in[17];
    const float* g_c2 = (const float*)d_in[18];
    const float* b_c2 = (const float*)d_in[19];
    const float* g_t1 = (const float*)d_in[20];
    const float* b_t1 = (const float*)d_in[21];
    const float* g_t2 = (const float*)d_in[22];
    const float* b_t2 = (const float*)d_in[23];

    const long long NTOK = 2097152;          // 8192 tokens * 256
    const int SLOT_MAX = 16896;              // 16384 + 8*64 alignment headroom
    float* dout = (float*)d_out;             // fp32: xc | xt | aux
    float* xcout = dout;
    float* xtout = dout + NTOK;

    float* ws = (float*)d_ws;
    float* Q   = ws;                         // reused as P1 post-attention
    float* Kp  = Q  + NTOK;
    float* Vp  = Kp + NTOK;
    float* O   = Vp + NTOK;
    float* X1  = O  + NTOK;
    float* Hs  = X1 + NTOK;                  // [SLOT_MAX][1024]
    float* Ys  = Hs + (long long)SLOT_MAX * 1024;   // [SLOT_MAX][256]
    float* counts      = Ys + (long long)SLOT_MAX * 256;  // 16
    float* gate_of_tok = counts + 16;        // 16384
    int* ip          = (int*)(gate_of_tok + 16384);
    int* gcount      = ip;                   // 16 (8 per pass)
    int* ebase       = ip + 16;              // 16 (9 used)
    int* pos_of_tok  = ip + 32;              // 16384
    int* exp_of_tok  = pos_of_tok + 16384;   // 16384
    int* tok_of_slot = exp_of_tok + 16384;   // 16896
    float* Sb        = (float*)(tok_of_slot + SLOT_MAX);

    const long long S_PER = 2048LL * 2048LL;
    const size_t base_bytes = (size_t)((char*)Sb - (char*)ws);
    int nb = 1;
    if (ws_size >= base_bytes + 16 * (size_t)S_PER * 4) nb = 16;
    else if (ws_size >= base_bytes + 4 * (size_t)S_PER * 4) nb = 4;

    hipMemsetAsync(counts, 0, 16 * sizeof(float), stream);
    hipMemsetAsync(gcount, 0, 16 * sizeof(int), stream);

    for (int pass = 0; pass < 2; pass++) {
        const float* xq  = pass ? Xt : Xc;
        const float* xkv = pass ? xcout : Xc;   // cross-att KV = finished context
        const float* g1  = pass ? g_t1 : g_c1;
        const float* be1 = pass ? b_t1 : b_c1;
        const float* g2  = pass ? g_t2 : g_c2;
        const float* be2 = pass ? b_t2 : b_c2;
        float* cnt = counts + pass * 8;
        int* gcnt  = gcount + pass * 8;
        float* oln = pass ? xtout : xcout;
        float* P1  = Q;

        // Q/K/V projections
        gemm_kernel<false,true><<<dim3(4,128,1),256,0,stream>>>(
            xq,  Wq, Q,  bq, 8192, 256, 256, 256, 256, 256, 0, 0, 0);
        gemm_kernel<false,true><<<dim3(4,128,1),256,0,stream>>>(
            xkv, Wk, Kp, bk, 8192, 256, 256, 256, 256, 256, 0, 0, 0);
        gemm_kernel<false,true><<<dim3(4,128,1),256,0,stream>>>(
            xkv, Wv, Vp, bv, 8192, 256, 256, 256, 256, 256, 0, 0, 0);

        // attention per (b,h)
        for (int z0 = 0; z0 < 16; z0 += nb) {
            gemm_kernel<true,false><<<dim3(32,32,nb),256,0,stream>>>(
                Q + 64 * z0, Kp + 64 * z0, Sb, nullptr,
                2048, 2048, 64, 1024, 1024, 2048, 64, 64, S_PER);
            softmax_kernel<<<dim3(2048,1,nb),256,0,stream>>>(Sb, S_PER, 0.125f);
            gemm_kernel<false,false><<<dim3(1,32,nb),256,0,stream>>>(
                Sb, Vp + 64 * z0, O + 64 * z0, nullptr,
                2048, 64, 2048, 2048, 1024, 1024, S_PER, 64, 64);
        }

        // output projection + LN1
        gemm_kernel<false,true><<<dim3(4,128,1),256,0,stream>>>(
            O, Wo, P1, bo, 8192, 256, 256, 256, 256, 256, 0, 0, 0);
        ln_kernel<<<2048,256,0,stream>>>(P1, xq, g1, be1, X1);

        // ---- sparse top-2 MoE ----
        hipMemsetAsync(tok_of_slot, 0, SLOT_MAX * sizeof(int), stream);
        gating_kernel<<<32,256,0,stream>>>(X1, Wg, bg, gcnt, cnt,
                                           pos_of_tok, exp_of_tok, gate_of_tok);
        finalize_kernel<<<1,64,0,stream>>>(gcnt, ebase);
        scatter_kernel<<<64,256,0,stream>>>(pos_of_tok, exp_of_tok, ebase, tok_of_slot);
        moe_gemm_kernel<true,true><<<dim3(16,264),256,0,stream>>>(
            X1, tok_of_slot, W1, b1, Hs, ebase,
            1024, 256, 256, 1024, 1024, 262144, 1024);
        moe_gemm_kernel<false,false><<<dim3(4,264),256,0,stream>>>(
            Hs, nullptr, W2, b2, Ys, ebase,
            256, 1024, 1024, 256, 256, 262144, 256);
        moe_combine_ln_kernel<<<2048,256,0,stream>>>(
            Ys, X1, pos_of_tok, exp_of_tok, gate_of_tok, ebase, g2, be2, oln);
    }

    aux_kernel<<<1,64,0,stream>>>(counts, dout + 2 * NTOK);
}

// Round 4
// 637.724 us; speedup vs baseline: 6.9511x; 2.5770x over previous
//
#include <hip/hip_runtime.h>
#include <hip/hip_bf16.h>

typedef _Float16 f16_t;
typedef _Float16 f16x8 __attribute__((ext_vector_type(8)));
typedef float f32x4 __attribute__((ext_vector_type(4)));

// ================= generic f16 GEMM: C[M,N] = A[M,K] @ B^T (B stored [N][K]) ==========
template<bool BIAS, bool OUTF16>
__global__ __launch_bounds__(256) void gemm16_kernel(
    const f16_t* __restrict__ A, const f16_t* __restrict__ B, void* __restrict__ Cv,
    const float* __restrict__ bias, int M, int N, int K, int lda, int ldb, int ldc)
{
    __shared__ f16_t As[64][72];
    __shared__ f16_t Bs[64][72];
    const int m0 = blockIdx.y * 64, n0 = blockIdx.x * 64;
    const int t = threadIdx.x, wave = t >> 6, lane = t & 63;
    const int wr = (wave >> 1) * 32, wc = (wave & 1) * 32;
    const int lr = lane & 15, kg = lane >> 4;
    const int sr = t >> 2, sc = (t & 3) * 16;
    const f16_t* arp = A + (long long)(m0 + sr) * lda;
    const f16_t* brp = B + (long long)(n0 + sr) * ldb;

    f32x4 acc[2][2] = {};
    for (int k0 = 0; k0 < K; k0 += 64) {
        *reinterpret_cast<f16x8*>(&As[sr][sc])     = *reinterpret_cast<const f16x8*>(&arp[k0 + sc]);
        *reinterpret_cast<f16x8*>(&As[sr][sc + 8]) = *reinterpret_cast<const f16x8*>(&arp[k0 + sc + 8]);
        *reinterpret_cast<f16x8*>(&Bs[sr][sc])     = *reinterpret_cast<const f16x8*>(&brp[k0 + sc]);
        *reinterpret_cast<f16x8*>(&Bs[sr][sc + 8]) = *reinterpret_cast<const f16x8*>(&brp[k0 + sc + 8]);
        __syncthreads();
        #pragma unroll
        for (int c = 0; c < 2; c++) {
            f16x8 a0 = *reinterpret_cast<const f16x8*>(&As[wr + lr][c * 32 + kg * 8]);
            f16x8 a1 = *reinterpret_cast<const f16x8*>(&As[wr + 16 + lr][c * 32 + kg * 8]);
            f16x8 b0 = *reinterpret_cast<const f16x8*>(&Bs[wc + lr][c * 32 + kg * 8]);
            f16x8 b1 = *reinterpret_cast<const f16x8*>(&Bs[wc + 16 + lr][c * 32 + kg * 8]);
            acc[0][0] = __builtin_amdgcn_mfma_f32_16x16x32_f16(a0, b0, acc[0][0], 0, 0, 0);
            acc[0][1] = __builtin_amdgcn_mfma_f32_16x16x32_f16(a0, b1, acc[0][1], 0, 0, 0);
            acc[1][0] = __builtin_amdgcn_mfma_f32_16x16x32_f16(a1, b0, acc[1][0], 0, 0, 0);
            acc[1][1] = __builtin_amdgcn_mfma_f32_16x16x32_f16(a1, b1, acc[1][1], 0, 0, 0);
        }
        __syncthreads();
    }
    #pragma unroll
    for (int mi = 0; mi < 2; mi++)
        #pragma unroll
        for (int ni = 0; ni < 2; ni++)
            #pragma unroll
            for (int r = 0; r < 4; r++) {
                const int row = m0 + wr + mi * 16 + kg * 4 + r;
                const int col = n0 + wc + ni * 16 + lr;
                float v = acc[mi][ni][r];
                if constexpr (BIAS) v += bias[col];
                if constexpr (OUTF16) ((f16_t*)Cv)[(long long)row * ldc + col] = (f16_t)v;
                else                  ((float*)Cv)[(long long)row * ldc + col] = v;
            }
}

// ================= MoE f16 GEMM (slot-compacted; expert from block row) =================
template<bool GATHER, bool RELU, bool OUTF16>
__global__ __launch_bounds__(256) void moe_gemm16_kernel(
    const f16_t* __restrict__ A, const int* __restrict__ tok_of_slot,
    const f16_t* __restrict__ W, const float* __restrict__ bias,
    void* __restrict__ Cv, const int* __restrict__ ebase,
    int N, int K, int lda, int ldb, int ldc, int wstride, int bstride)
{
    const int m0 = blockIdx.y * 64;
    if (m0 >= ebase[8]) return;
    int e = 0;
    #pragma unroll
    for (int i = 1; i < 8; i++) if (m0 >= ebase[i]) e = i;
    const f16_t* __restrict__ B = W + (long long)e * wstride;
    const float* __restrict__ bs = bias + e * bstride;

    __shared__ f16_t As[64][72];
    __shared__ f16_t Bs[64][72];
    const int n0 = blockIdx.x * 64;
    const int t = threadIdx.x, wave = t >> 6, lane = t & 63;
    const int wr = (wave >> 1) * 32, wc = (wave & 1) * 32;
    const int lr = lane & 15, kg = lane >> 4;
    const int sr = t >> 2, sc = (t & 3) * 16;
    const f16_t* arp;
    if constexpr (GATHER) arp = A + (long long)tok_of_slot[m0 + sr] * lda;
    else                  arp = A + (long long)(m0 + sr) * lda;
    const f16_t* brp = B + (long long)(n0 + sr) * ldb;

    f32x4 acc[2][2] = {};
    for (int k0 = 0; k0 < K; k0 += 64) {
        *reinterpret_cast<f16x8*>(&As[sr][sc])     = *reinterpret_cast<const f16x8*>(&arp[k0 + sc]);
        *reinterpret_cast<f16x8*>(&As[sr][sc + 8]) = *reinterpret_cast<const f16x8*>(&arp[k0 + sc + 8]);
        *reinterpret_cast<f16x8*>(&Bs[sr][sc])     = *reinterpret_cast<const f16x8*>(&brp[k0 + sc]);
        *reinterpret_cast<f16x8*>(&Bs[sr][sc + 8]) = *reinterpret_cast<const f16x8*>(&brp[k0 + sc + 8]);
        __syncthreads();
        #pragma unroll
        for (int c = 0; c < 2; c++) {
            f16x8 a0 = *reinterpret_cast<const f16x8*>(&As[wr + lr][c * 32 + kg * 8]);
            f16x8 a1 = *reinterpret_cast<const f16x8*>(&As[wr + 16 + lr][c * 32 + kg * 8]);
            f16x8 b0 = *reinterpret_cast<const f16x8*>(&Bs[wc + lr][c * 32 + kg * 8]);
            f16x8 b1 = *reinterpret_cast<const f16x8*>(&Bs[wc + 16 + lr][c * 32 + kg * 8]);
            acc[0][0] = __builtin_amdgcn_mfma_f32_16x16x32_f16(a0, b0, acc[0][0], 0, 0, 0);
            acc[0][1] = __builtin_amdgcn_mfma_f32_16x16x32_f16(a0, b1, acc[0][1], 0, 0, 0);
            acc[1][0] = __builtin_amdgcn_mfma_f32_16x16x32_f16(a1, b0, acc[1][0], 0, 0, 0);
            acc[1][1] = __builtin_amdgcn_mfma_f32_16x16x32_f16(a1, b1, acc[1][1], 0, 0, 0);
        }
        __syncthreads();
    }
    #pragma unroll
    for (int mi = 0; mi < 2; mi++)
        #pragma unroll
        for (int ni = 0; ni < 2; ni++)
            #pragma unroll
            for (int r = 0; r < 4; r++) {
                const int row = m0 + wr + mi * 16 + kg * 4 + r;
                const int col = n0 + wc + ni * 16 + lr;
                float v = acc[mi][ni][r] + bs[col];
                if constexpr (RELU) v = fmaxf(v, 0.f);
                if constexpr (OUTF16) ((f16_t*)Cv)[(long long)row * ldc + col] = (f16_t)v;
                else                  ((float*)Cv)[(long long)row * ldc + col] = v;
            }
}

// ================= flash attention: one block per (q-tile 64, bh) =================
// Q/K/V/O f16 [8192][256], bh z: row s at s*1024 + 64*z, dh=64, Sk=2048.
__global__ __launch_bounds__(256) void flash_kernel(
    const f16_t* __restrict__ Q16, const f16_t* __restrict__ K16,
    const f16_t* __restrict__ V16, f16_t* __restrict__ O16)
{
    __shared__ f16_t Ks[64][72];
    __shared__ f16_t VsT[64][72];
    __shared__ f16_t Ps[4][16][72];

    const int z = blockIdx.y;
    const int m0 = blockIdx.x * 64;
    const int t = threadIdx.x, w = t >> 6, lane = t & 63;
    const int lr = lane & 15, kg = lane >> 4;
    const long long cbase = 64LL * z;

    // Q fragments in registers (16 rows per wave, 2 k-chunks)
    f16x8 qf0, qf1;
    {
        const long long qrow = (long long)(m0 + w * 16 + lr) * 1024 + cbase;
        qf0 = *reinterpret_cast<const f16x8*>(&Q16[qrow + kg * 8]);
        qf1 = *reinterpret_cast<const f16x8*>(&Q16[qrow + 32 + kg * 8]);
    }

    f32x4 oacc[4] = {};
    float mrun[4] = { -1e30f, -1e30f, -1e30f, -1e30f };
    float lrun[4] = {};

    const int sr = t >> 2, sc = (t & 3) * 16;
    for (int n0 = 0; n0 < 2048; n0 += 64) {
        // ---- stage K (as rows) and V (transposed) ----
        const long long krow = (long long)(n0 + sr) * 1024 + cbase;
        f16x8 kv0 = *reinterpret_cast<const f16x8*>(&K16[krow + sc]);
        f16x8 kv1 = *reinterpret_cast<const f16x8*>(&K16[krow + sc + 8]);
        f16x8 vv0 = *reinterpret_cast<const f16x8*>(&V16[krow + sc]);
        f16x8 vv1 = *reinterpret_cast<const f16x8*>(&V16[krow + sc + 8]);
        *reinterpret_cast<f16x8*>(&Ks[sr][sc])     = kv0;
        *reinterpret_cast<f16x8*>(&Ks[sr][sc + 8]) = kv1;
        #pragma unroll
        for (int i = 0; i < 8; i++) {
            VsT[sc + i][sr]     = vv0[i];
            VsT[sc + 8 + i][sr] = vv1[i];
        }
        __syncthreads();

        // ---- S = Q K^T * scale (per wave: 16 rows x 64 cols) ----
        float sv[4][4];
        #pragma unroll
        for (int nt = 0; nt < 4; nt++) {
            f32x4 acc = {};
            f16x8 b0 = *reinterpret_cast<const f16x8*>(&Ks[nt * 16 + lr][kg * 8]);
            f16x8 b1 = *reinterpret_cast<const f16x8*>(&Ks[nt * 16 + lr][32 + kg * 8]);
            acc = __builtin_amdgcn_mfma_f32_16x16x32_f16(qf0, b0, acc, 0, 0, 0);
            acc = __builtin_amdgcn_mfma_f32_16x16x32_f16(qf1, b1, acc, 0, 0, 0);
            #pragma unroll
            for (int r = 0; r < 4; r++) sv[nt][r] = acc[r] * 0.125f;
        }

        // ---- online softmax (row = kg*4 + r; reduce over 16-lane group) ----
        float mnew[4], alpha[4];
        #pragma unroll
        for (int r = 0; r < 4; r++) {
            float rm = fmaxf(fmaxf(sv[0][r], sv[1][r]), fmaxf(sv[2][r], sv[3][r]));
            rm = fmaxf(rm, __shfl_xor(rm, 1));
            rm = fmaxf(rm, __shfl_xor(rm, 2));
            rm = fmaxf(rm, __shfl_xor(rm, 4));
            rm = fmaxf(rm, __shfl_xor(rm, 8));
            mnew[r] = fmaxf(mrun[r], rm);
            alpha[r] = __expf(mrun[r] - mnew[r]);
            mrun[r] = mnew[r];
        }
        #pragma unroll
        for (int nt = 0; nt < 4; nt++)
            #pragma unroll
            for (int r = 0; r < 4; r++) sv[nt][r] = __expf(sv[nt][r] - mnew[r]);
        #pragma unroll
        for (int r = 0; r < 4; r++) {
            float rs = sv[0][r] + sv[1][r] + sv[2][r] + sv[3][r];
            rs += __shfl_xor(rs, 1);
            rs += __shfl_xor(rs, 2);
            rs += __shfl_xor(rs, 4);
            rs += __shfl_xor(rs, 8);
            lrun[r] = lrun[r] * alpha[r] + rs;
        }
        #pragma unroll
        for (int dt = 0; dt < 4; dt++)
            #pragma unroll
            for (int r = 0; r < 4; r++) oacc[dt][r] *= alpha[r];

        // ---- P: C-layout -> A-layout via per-wave LDS (same-wave, no barrier) ----
        #pragma unroll
        for (int nt = 0; nt < 4; nt++)
            #pragma unroll
            for (int r = 0; r < 4; r++)
                Ps[w][kg * 4 + r][nt * 16 + lr] = (f16_t)sv[nt][r];

        f16x8 pa0 = *reinterpret_cast<const f16x8*>(&Ps[w][lr][kg * 8]);
        f16x8 pa1 = *reinterpret_cast<const f16x8*>(&Ps[w][lr][32 + kg * 8]);
        #pragma unroll
        for (int dt = 0; dt < 4; dt++) {
            f16x8 vb0 = *reinterpret_cast<const f16x8*>(&VsT[dt * 16 + lr][kg * 8]);
            f16x8 vb1 = *reinterpret_cast<const f16x8*>(&VsT[dt * 16 + lr][32 + kg * 8]);
            oacc[dt] = __builtin_amdgcn_mfma_f32_16x16x32_f16(pa0, vb0, oacc[dt], 0, 0, 0);
            oacc[dt] = __builtin_amdgcn_mfma_f32_16x16x32_f16(pa1, vb1, oacc[dt], 0, 0, 0);
        }
        __syncthreads();
    }

    const long long orow0 = (long long)(m0 + w * 16) * 1024 + cbase;
    #pragma unroll
    for (int r = 0; r < 4; r++) {
        const float inv = 1.f / lrun[r];
        #pragma unroll
        for (int dt = 0; dt < 4; dt++)
            O16[orow0 + (long long)(kg * 4 + r) * 1024 + dt * 16 + lr] =
                (f16_t)(oacc[dt][r] * inv);
    }
}

// ================= prep: weight transpose-convert, activation convert =================
// out[C][R] f16 from in[R][C] f32 (per z slab)
__global__ __launch_bounds__(256) void wtrans_kernel(
    const float* __restrict__ in, f16_t* __restrict__ out, int R, int C)
{
    __shared__ float tile[32][33];
    const long long zoff = (long long)blockIdx.z * R * C;
    const int r0 = blockIdx.y * 32, c0 = blockIdx.x * 32;
    const int tx = threadIdx.x & 31, ty = threadIdx.x >> 5;
    #pragma unroll
    for (int i = 0; i < 32; i += 8)
        tile[ty + i][tx] = in[zoff + (long long)(r0 + ty + i) * C + c0 + tx];
    __syncthreads();
    #pragma unroll
    for (int i = 0; i < 32; i += 8)
        out[zoff + (long long)(c0 + ty + i) * R + r0 + tx] = (f16_t)tile[tx][ty + i];
}

__global__ __launch_bounds__(256) void cvt16_kernel(
    const float* __restrict__ in, f16_t* __restrict__ out)
{
    const long long i = ((long long)blockIdx.x * 256 + threadIdx.x) * 4;
    float4 v = *reinterpret_cast<const float4*>(&in[i]);
    f16_t o[4] = { (f16_t)v.x, (f16_t)v.y, (f16_t)v.z, (f16_t)v.w };
    *reinterpret_cast<ulong1*>(&out[i]) = *reinterpret_cast<ulong1*>(o);
}

// ================= LN(in1+in2)*g+b -> f32 (+optional f16) =================
__global__ __launch_bounds__(256) void ln_kernel(
    const float* __restrict__ in1, const float* __restrict__ in2,
    const float* __restrict__ gamma, const float* __restrict__ beta,
    float* __restrict__ out, f16_t* __restrict__ out16)
{
    const int wave = threadIdx.x >> 6, lane = threadIdx.x & 63;
    const long long row = (long long)blockIdx.x * 4 + wave;
    const long long base = row * 256 + lane * 4;
    float4 a = *reinterpret_cast<const float4*>(&in1[base]);
    float4 b = *reinterpret_cast<const float4*>(&in2[base]);
    float x[4] = { a.x + b.x, a.y + b.y, a.z + b.z, a.w + b.w };
    float s = x[0] + x[1] + x[2] + x[3];
    float s2 = x[0]*x[0] + x[1]*x[1] + x[2]*x[2] + x[3]*x[3];
    #pragma unroll
    for (int o = 32; o; o >>= 1) { s += __shfl_xor(s, o); s2 += __shfl_xor(s2, o); }
    const float mean = s * (1.f / 256.f);
    const float var = s2 * (1.f / 256.f) - mean * mean;
    const float rstd = rsqrtf(var + 1e-5f);
    float4 g = *reinterpret_cast<const float4*>(&gamma[lane * 4]);
    float4 bb = *reinterpret_cast<const float4*>(&beta[lane * 4]);
    const float* gf = reinterpret_cast<const float*>(&g);
    const float* bf = reinterpret_cast<const float*>(&bb);
    float y[4];
    #pragma unroll
    for (int i = 0; i < 4; i++) y[i] = (x[i] - mean) * rstd * gf[i] + bf[i];
    *reinterpret_cast<float4*>(&out[base]) = make_float4(y[0], y[1], y[2], y[3]);
    if (out16) {
        f16_t o[4] = { (f16_t)y[0], (f16_t)y[1], (f16_t)y[2], (f16_t)y[3] };
        *reinterpret_cast<ulong1*>(&out16[base]) = *reinterpret_cast<ulong1*>(o);
    }
}

// ================= gating (1 thread/token, hierarchical) =================
__global__ __launch_bounds__(256) void gating_kernel(
    const float* __restrict__ X, const float* __restrict__ Wg, const float* __restrict__ bg,
    int* __restrict__ gcount, float* __restrict__ counts,
    int* __restrict__ pos_of_tok, int* __restrict__ exp_of_tok,
    float* __restrict__ gate_of_tok)
{
    __shared__ float WgL[2048];
    __shared__ float cpart[8];
    __shared__ int lcnt[8];
    __shared__ int lbase[8];
    const int t = threadIdx.x;
    for (int i = t; i < 2048; i += 256) WgL[i] = Wg[i];
    if (t < 8) { cpart[t] = 0.f; lcnt[t] = 0; }
    __syncthreads();

    const int tok = blockIdx.x * 256 + t;
    const float* xr = X + (long long)tok * 256;
    float acc[8] = {};
    for (int k = 0; k < 256; k += 4) {
        float4 xv = *reinterpret_cast<const float4*>(xr + k);
        const float* xf = reinterpret_cast<const float*>(&xv);
        #pragma unroll
        for (int i = 0; i < 4; i++) {
            const float xi = xf[i];
            const float* wrow = &WgL[(k + i) * 8];
            #pragma unroll
            for (int e = 0; e < 8; e++) acc[e] += xi * wrow[e];
        }
    }
    float p[8]; float mx = -1e30f;
    #pragma unroll
    for (int e = 0; e < 8; e++) { p[e] = acc[e] + bg[e]; mx = fmaxf(mx, p[e]); }
    float se = 0.f;
    #pragma unroll
    for (int e = 0; e < 8; e++) { p[e] = __expf(p[e] - mx); se += p[e]; }
    const float inv = 1.f / se;
    #pragma unroll
    for (int e = 0; e < 8; e++) { p[e] *= inv; atomicAdd(&cpart[e], p[e]); }

    int i1 = 0;
    #pragma unroll
    for (int e = 1; e < 8; e++) if (p[e] > p[i1]) i1 = e;
    int i2 = (i1 == 0) ? 1 : 0;
    #pragma unroll
    for (int e = 0; e < 8; e++) if (e != i1 && p[e] > p[i2]) i2 = e;
    const float gs = 1.f / (p[i1] + p[i2]);

    const int p1 = atomicAdd(&lcnt[i1], 1);
    const int p2 = atomicAdd(&lcnt[i2], 1);
    __syncthreads();
    if (t < 8) {
        lbase[t] = atomicAdd(&gcount[t], lcnt[t]);
        atomicAdd(&counts[t], cpart[t]);
    }
    __syncthreads();
    pos_of_tok[2 * tok]     = lbase[i1] + p1;
    pos_of_tok[2 * tok + 1] = lbase[i2] + p2;
    exp_of_tok[2 * tok]     = i1;
    exp_of_tok[2 * tok + 1] = i2;
    gate_of_tok[2 * tok]     = p[i1] * gs;
    gate_of_tok[2 * tok + 1] = p[i2] * gs;
}

__global__ void finalize_kernel(const int* __restrict__ gcount, int* __restrict__ ebase)
{
    if (threadIdx.x == 0) {
        int b = 0;
        for (int e = 0; e < 8; e++) { ebase[e] = b; b += (gcount[e] + 63) & ~63; }
        ebase[8] = b;
    }
}

__global__ __launch_bounds__(256) void scatter_kernel(
    const int* __restrict__ pos_of_tok, const int* __restrict__ exp_of_tok,
    const int* __restrict__ ebase, int* __restrict__ tok_of_slot)
{
    const int i = blockIdx.x * 256 + threadIdx.x;
    const int e = exp_of_tok[i];
    tok_of_slot[ebase[e] + pos_of_tok[i]] = i >> 1;
}

// out = LN(gv1*Ys[s1] + gv2*Ys[s2] + X1), optional f16 copy
__global__ __launch_bounds__(256) void moe_combine_ln_kernel(
    const float* __restrict__ Ys, const float* __restrict__ X1,
    const int* __restrict__ pos_of_tok, const int* __restrict__ exp_of_tok,
    const float* __restrict__ gate_of_tok, const int* __restrict__ ebase,
    const float* __restrict__ gamma, const float* __restrict__ beta,
    float* __restrict__ out, f16_t* __restrict__ out16)
{
    const int wave = threadIdx.x >> 6, lane = threadIdx.x & 63;
    const long long tok = (long long)blockIdx.x * 4 + wave;
    const int e1 = exp_of_tok[2 * tok], e2 = exp_of_tok[2 * tok + 1];
    const long long s1 = ebase[e1] + pos_of_tok[2 * tok];
    const long long s2 = ebase[e2] + pos_of_tok[2 * tok + 1];
    const float gv1 = gate_of_tok[2 * tok], gv2 = gate_of_tok[2 * tok + 1];
    const long long base = tok * 256 + lane * 4;
    float4 y1 = *reinterpret_cast<const float4*>(&Ys[s1 * 256 + lane * 4]);
    float4 y2 = *reinterpret_cast<const float4*>(&Ys[s2 * 256 + lane * 4]);
    float4 xv = *reinterpret_cast<const float4*>(&X1[base]);
    float x[4] = { gv1 * y1.x + gv2 * y2.x + xv.x,
                   gv1 * y1.y + gv2 * y2.y + xv.y,
                   gv1 * y1.z + gv2 * y2.z + xv.z,
                   gv1 * y1.w + gv2 * y2.w + xv.w };
    float s = x[0] + x[1] + x[2] + x[3];
    float s2v = x[0]*x[0] + x[1]*x[1] + x[2]*x[2] + x[3]*x[3];
    #pragma unroll
    for (int o = 32; o; o >>= 1) { s += __shfl_xor(s, o); s2v += __shfl_xor(s2v, o); }
    const float mean = s * (1.f / 256.f);
    const float var = s2v * (1.f / 256.f) - mean * mean;
    const float rstd = rsqrtf(var + 1e-5f);
    float4 g = *reinterpret_cast<const float4*>(&gamma[lane * 4]);
    float4 bb = *reinterpret_cast<const float4*>(&beta[lane * 4]);
    const float* gf = reinterpret_cast<const float*>(&g);
    const float* bf = reinterpret_cast<const float*>(&bb);
    float y[4];
    #pragma unroll
    for (int i = 0; i < 4; i++) y[i] = (x[i] - mean) * rstd * gf[i] + bf[i];
    *reinterpret_cast<float4*>(&out[base]) = make_float4(y[0], y[1], y[2], y[3]);
    if (out16) {
        f16_t o[4] = { (f16_t)y[0], (f16_t)y[1], (f16_t)y[2], (f16_t)y[3] };
        *reinterpret_cast<ulong1*>(&out16[base]) = *reinterpret_cast<ulong1*>(o);
    }
}

__global__ void aux_kernel(const float* __restrict__ counts, float* __restrict__ out)
{
    if (threadIdx.x == 0) {
        float aux = 0.f;
        for (int pzz = 0; pzz < 2; pzz++) {
            const float* c = counts + pzz * 8;
            float tot = 0.f;
            for (int e = 0; e < 8; e++) tot += c[e];
            float s = 0.f;
            for (int e = 0; e < 8; e++) s += (c[e] / tot) * (c[e] * (1.f / 8192.f));
            aux += 8.f * s;
        }
        out[0] = 0.01f * aux;
    }
}

extern "C" void kernel_launch(void* const* d_in, const int* in_sizes, int n_in,
                              void* d_out, int out_size, void* d_ws, size_t ws_size,
                              hipStream_t stream)
{
    const float* Xc  = (const float*)d_in[0];
    const float* Xt  = (const float*)d_in[1];
    const float* Wq  = (const float*)d_in[2];
    const float* Wk  = (const float*)d_in[3];
    const float* Wv  = (const float*)d_in[4];
    const float* bq  = (const float*)d_in[5];
    const float* bk  = (const float*)d_in[6];
    const float* bv  = (const float*)d_in[7];
    const float* Wo  = (const float*)d_in[8];
    const float* bo  = (const float*)d_in[9];
    const float* Wg  = (const float*)d_in[10];
    const float* bg  = (const float*)d_in[11];
    const float* W1  = (const float*)d_in[12];
    const float* b1  = (const float*)d_in[13];
    const float* W2  = (const float*)d_in[14];
    const float* b2  = (const float*)d_in[15];
    const float* g_c1 = (const float*)d_in[16];
    const float* b_c1 = (const float*)d_in[17];
    const float* g_c2 = (const float*)d_in[18];
    const float* b_c2 = (const float*)d_in[19];
    const float* g_t1 = (const float*)d_in[20];
    const float* b_t1 = (const float*)d_in[21];
    const float* g_t2 = (const float*)d_in[22];
    const float* b_t2 = (const float*)d_in[23];

    const long long NTOK = 2097152;          // 8192 tokens * 256
    const int SLOT_MAX = 16896;              // 264 * 64
    float* dout = (float*)d_out;             // fp32: xc | xt | aux
    float* xcout = dout;
    float* xtout = dout + NTOK;

    float* ws = (float*)d_ws;
    float* P1 = ws;
    float* X1 = P1 + NTOK;
    float* Ys = X1 + NTOK;                               // SLOT_MAX x 256
    float* counts      = Ys + (long long)SLOT_MAX * 256; // 16
    float* gate_of_tok = counts + 16;                    // 16384
    int* gcount      = (int*)(gate_of_tok + 16384);      // 16
    int* ebase       = gcount + 16;                      // 16
    int* pos_of_tok  = ebase + 16;                       // 16384
    int* exp_of_tok  = pos_of_tok + 16384;               // 16384
    int* tok_of_slot = exp_of_tok + 16384;               // SLOT_MAX
    f16_t* h16 = (f16_t*)(tok_of_slot + SLOT_MAX);
    f16_t* Xc16 = h16;
    f16_t* Xt16 = Xc16 + NTOK;
    f16_t* xc16 = Xt16 + NTOK;
    f16_t* Q16  = xc16 + NTOK;
    f16_t* K16  = Q16 + NTOK;
    f16_t* V16  = K16 + NTOK;
    f16_t* O16  = V16 + NTOK;
    f16_t* X116 = O16 + NTOK;
    f16_t* Hs16 = X116 + NTOK;                           // SLOT_MAX x 1024
    f16_t* WqT  = Hs16 + (long long)SLOT_MAX * 1024;
    f16_t* WkT  = WqT + 65536;
    f16_t* WvT  = WkT + 65536;
    f16_t* WoT  = WvT + 65536;
    f16_t* W1T  = WoT + 65536;                           // 8 x 1024 x 256
    f16_t* W2T  = W1T + 2097152;                         // 8 x 256 x 1024

    hipMemsetAsync(counts, 0, 16 * sizeof(float), stream);
    hipMemsetAsync(gcount, 0, 16 * sizeof(int), stream);

    // ---- prep: f16 conversions + weight transposes ----
    cvt16_kernel<<<2048, 256, 0, stream>>>(Xc, Xc16);
    cvt16_kernel<<<2048, 256, 0, stream>>>(Xt, Xt16);
    wtrans_kernel<<<dim3(8, 8, 1), 256, 0, stream>>>(Wq, WqT, 256, 256);
    wtrans_kernel<<<dim3(8, 8, 1), 256, 0, stream>>>(Wk, WkT, 256, 256);
    wtrans_kernel<<<dim3(8, 8, 1), 256, 0, stream>>>(Wv, WvT, 256, 256);
    wtrans_kernel<<<dim3(8, 8, 1), 256, 0, stream>>>(Wo, WoT, 256, 256);
    wtrans_kernel<<<dim3(32, 8, 8), 256, 0, stream>>>(W1, W1T, 256, 1024);
    wtrans_kernel<<<dim3(8, 32, 8), 256, 0, stream>>>(W2, W2T, 1024, 256);

    for (int pass = 0; pass < 2; pass++) {
        const float*  xq    = pass ? Xt   : Xc;     // fp32 residual
        const f16_t*  xq16  = pass ? Xt16 : Xc16;
        const f16_t*  xkv16 = pass ? xc16 : Xc16;   // cross-att KV = finished context
        const float* g1  = pass ? g_t1 : g_c1;
        const float* be1 = pass ? b_t1 : b_c1;
        const float* g2  = pass ? g_t2 : g_c2;
        const float* be2 = pass ? b_t2 : b_c2;
        float* cnt = counts + pass * 8;
        int* gcnt  = gcount + pass * 8;
        float* oln = pass ? xtout : xcout;
        f16_t* oln16 = pass ? nullptr : xc16;

        // Q/K/V projections -> f16
        gemm16_kernel<true,true><<<dim3(4,128), 256, 0, stream>>>(
            xq16,  WqT, Q16, bq, 8192, 256, 256, 256, 256, 256);
        gemm16_kernel<true,true><<<dim3(4,128), 256, 0, stream>>>(
            xkv16, WkT, K16, bk, 8192, 256, 256, 256, 256, 256);
        gemm16_kernel<true,true><<<dim3(4,128), 256, 0, stream>>>(
            xkv16, WvT, V16, bv, 8192, 256, 256, 256, 256, 256);

        // fused attention
        flash_kernel<<<dim3(32, 16), 256, 0, stream>>>(Q16, K16, V16, O16);

        // output projection + LN1 (dual f32/f16)
        gemm16_kernel<true,false><<<dim3(4,128), 256, 0, stream>>>(
            O16, WoT, P1, bo, 8192, 256, 256, 256, 256, 256);
        ln_kernel<<<2048, 256, 0, stream>>>(P1, xq, g1, be1, X1, X116);

        // ---- sparse top-2 MoE ----
        hipMemsetAsync(tok_of_slot, 0, SLOT_MAX * sizeof(int), stream);
        gating_kernel<<<32, 256, 0, stream>>>(X1, Wg, bg, gcnt, cnt,
                                              pos_of_tok, exp_of_tok, gate_of_tok);
        finalize_kernel<<<1, 64, 0, stream>>>(gcnt, ebase);
        scatter_kernel<<<64, 256, 0, stream>>>(pos_of_tok, exp_of_tok, ebase, tok_of_slot);
        moe_gemm16_kernel<true,true,true><<<dim3(16, 264), 256, 0, stream>>>(
            X116, tok_of_slot, W1T, b1, Hs16, ebase,
            1024, 256, 256, 256, 1024, 262144, 1024);
        moe_gemm16_kernel<false,false,false><<<dim3(4, 264), 256, 0, stream>>>(
            Hs16, nullptr, W2T, b2, Ys, ebase,
            256, 1024, 1024, 1024, 256, 262144, 256);
        moe_combine_ln_kernel<<<2048, 256, 0, stream>>>(
            Ys, X1, pos_of_tok, exp_of_tok, gate_of_tok, ebase, g2, be2, oln, oln16);
    }

    aux_kernel<<<1, 64, 0, stream>>>(counts, dout + 2 * NTOK);
}

// Round 5
// 591.795 us; speedup vs baseline: 7.4906x; 1.0776x over previous
//
#include <hip/hip_runtime.h>
#include <hip/hip_bf16.h>

typedef _Float16 f16_t;
typedef _Float16 f16x8 __attribute__((ext_vector_type(8)));
typedef float f32x4 __attribute__((ext_vector_type(4)));

// ================= generic f16 GEMM: C[M,N] = A[M,K] @ B^T (B stored [N][K]) ==========
template<bool BIAS, bool OUTF16>
__global__ __launch_bounds__(256) void gemm16_kernel(
    const f16_t* __restrict__ A, const f16_t* __restrict__ B, void* __restrict__ Cv,
    const float* __restrict__ bias, int M, int N, int K, int lda, int ldb, int ldc)
{
    __shared__ f16_t As[64][72];
    __shared__ f16_t Bs[64][72];
    const int m0 = blockIdx.y * 64, n0 = blockIdx.x * 64;
    const int t = threadIdx.x, wave = t >> 6, lane = t & 63;
    const int wr = (wave >> 1) * 32, wc = (wave & 1) * 32;
    const int lr = lane & 15, kg = lane >> 4;
    const int sr = t >> 2, sc = (t & 3) * 16;
    const f16_t* arp = A + (long long)(m0 + sr) * lda;
    const f16_t* brp = B + (long long)(n0 + sr) * ldb;

    f32x4 acc[2][2] = {};
    for (int k0 = 0; k0 < K; k0 += 64) {
        *reinterpret_cast<f16x8*>(&As[sr][sc])     = *reinterpret_cast<const f16x8*>(&arp[k0 + sc]);
        *reinterpret_cast<f16x8*>(&As[sr][sc + 8]) = *reinterpret_cast<const f16x8*>(&arp[k0 + sc + 8]);
        *reinterpret_cast<f16x8*>(&Bs[sr][sc])     = *reinterpret_cast<const f16x8*>(&brp[k0 + sc]);
        *reinterpret_cast<f16x8*>(&Bs[sr][sc + 8]) = *reinterpret_cast<const f16x8*>(&brp[k0 + sc + 8]);
        __syncthreads();
        #pragma unroll
        for (int c = 0; c < 2; c++) {
            f16x8 a0 = *reinterpret_cast<const f16x8*>(&As[wr + lr][c * 32 + kg * 8]);
            f16x8 a1 = *reinterpret_cast<const f16x8*>(&As[wr + 16 + lr][c * 32 + kg * 8]);
            f16x8 b0 = *reinterpret_cast<const f16x8*>(&Bs[wc + lr][c * 32 + kg * 8]);
            f16x8 b1 = *reinterpret_cast<const f16x8*>(&Bs[wc + 16 + lr][c * 32 + kg * 8]);
            acc[0][0] = __builtin_amdgcn_mfma_f32_16x16x32_f16(a0, b0, acc[0][0], 0, 0, 0);
            acc[0][1] = __builtin_amdgcn_mfma_f32_16x16x32_f16(a0, b1, acc[0][1], 0, 0, 0);
            acc[1][0] = __builtin_amdgcn_mfma_f32_16x16x32_f16(a1, b0, acc[1][0], 0, 0, 0);
            acc[1][1] = __builtin_amdgcn_mfma_f32_16x16x32_f16(a1, b1, acc[1][1], 0, 0, 0);
        }
        __syncthreads();
    }
    #pragma unroll
    for (int mi = 0; mi < 2; mi++)
        #pragma unroll
        for (int ni = 0; ni < 2; ni++)
            #pragma unroll
            for (int r = 0; r < 4; r++) {
                const int row = m0 + wr + mi * 16 + kg * 4 + r;
                const int col = n0 + wc + ni * 16 + lr;
                float v = acc[mi][ni][r];
                if constexpr (BIAS) v += bias[col];
                if constexpr (OUTF16) ((f16_t*)Cv)[(long long)row * ldc + col] = (f16_t)v;
                else                  ((float*)Cv)[(long long)row * ldc + col] = v;
            }
}

// ================= fused Q/K/V projection: blockIdx.z picks {W,bias,out,A} ============
__global__ __launch_bounds__(256) void qkv_kernel(
    const f16_t* __restrict__ Aq, const f16_t* __restrict__ Akv,
    const f16_t* __restrict__ B0, const f16_t* __restrict__ B1, const f16_t* __restrict__ B2,
    const float* __restrict__ bi0, const float* __restrict__ bi1, const float* __restrict__ bi2,
    f16_t* __restrict__ C0, f16_t* __restrict__ C1, f16_t* __restrict__ C2)
{
    const int zz = blockIdx.z;
    const f16_t* A = (zz == 0) ? Aq : Akv;
    const f16_t* B = (zz == 0) ? B0 : (zz == 1 ? B1 : B2);
    const float* bias = (zz == 0) ? bi0 : (zz == 1 ? bi1 : bi2);
    f16_t* C = (zz == 0) ? C0 : (zz == 1 ? C1 : C2);

    __shared__ f16_t As[64][72];
    __shared__ f16_t Bs[64][72];
    const int m0 = blockIdx.y * 64, n0 = blockIdx.x * 64;
    const int t = threadIdx.x, wave = t >> 6, lane = t & 63;
    const int wr = (wave >> 1) * 32, wc = (wave & 1) * 32;
    const int lr = lane & 15, kg = lane >> 4;
    const int sr = t >> 2, sc = (t & 3) * 16;
    const f16_t* arp = A + (long long)(m0 + sr) * 256;
    const f16_t* brp = B + (long long)(n0 + sr) * 256;

    f32x4 acc[2][2] = {};
    for (int k0 = 0; k0 < 256; k0 += 64) {
        *reinterpret_cast<f16x8*>(&As[sr][sc])     = *reinterpret_cast<const f16x8*>(&arp[k0 + sc]);
        *reinterpret_cast<f16x8*>(&As[sr][sc + 8]) = *reinterpret_cast<const f16x8*>(&arp[k0 + sc + 8]);
        *reinterpret_cast<f16x8*>(&Bs[sr][sc])     = *reinterpret_cast<const f16x8*>(&brp[k0 + sc]);
        *reinterpret_cast<f16x8*>(&Bs[sr][sc + 8]) = *reinterpret_cast<const f16x8*>(&brp[k0 + sc + 8]);
        __syncthreads();
        #pragma unroll
        for (int c = 0; c < 2; c++) {
            f16x8 a0 = *reinterpret_cast<const f16x8*>(&As[wr + lr][c * 32 + kg * 8]);
            f16x8 a1 = *reinterpret_cast<const f16x8*>(&As[wr + 16 + lr][c * 32 + kg * 8]);
            f16x8 b0 = *reinterpret_cast<const f16x8*>(&Bs[wc + lr][c * 32 + kg * 8]);
            f16x8 b1 = *reinterpret_cast<const f16x8*>(&Bs[wc + 16 + lr][c * 32 + kg * 8]);
            acc[0][0] = __builtin_amdgcn_mfma_f32_16x16x32_f16(a0, b0, acc[0][0], 0, 0, 0);
            acc[0][1] = __builtin_amdgcn_mfma_f32_16x16x32_f16(a0, b1, acc[0][1], 0, 0, 0);
            acc[1][0] = __builtin_amdgcn_mfma_f32_16x16x32_f16(a1, b0, acc[1][0], 0, 0, 0);
            acc[1][1] = __builtin_amdgcn_mfma_f32_16x16x32_f16(a1, b1, acc[1][1], 0, 0, 0);
        }
        __syncthreads();
    }
    #pragma unroll
    for (int mi = 0; mi < 2; mi++)
        #pragma unroll
        for (int ni = 0; ni < 2; ni++)
            #pragma unroll
            for (int r = 0; r < 4; r++) {
                const int row = m0 + wr + mi * 16 + kg * 4 + r;
                const int col = n0 + wc + ni * 16 + lr;
                C[(long long)row * 256 + col] = (f16_t)(acc[mi][ni][r] + bias[col]);
            }
}

// ================= MoE f16 GEMM (slot-compacted; expert from block row) =================
template<bool GATHER, bool RELU, bool OUTF16>
__global__ __launch_bounds__(256) void moe_gemm16_kernel(
    const f16_t* __restrict__ A, const int* __restrict__ tok_of_slot,
    const f16_t* __restrict__ W, const float* __restrict__ bias,
    void* __restrict__ Cv, const int* __restrict__ ebase,
    int N, int K, int lda, int ldb, int ldc, int wstride, int bstride)
{
    const int m0 = blockIdx.y * 64;
    if (m0 >= ebase[8]) return;
    int e = 0;
    #pragma unroll
    for (int i = 1; i < 8; i++) if (m0 >= ebase[i]) e = i;
    const f16_t* __restrict__ B = W + (long long)e * wstride;
    const float* __restrict__ bs = bias + e * bstride;

    __shared__ f16_t As[64][72];
    __shared__ f16_t Bs[64][72];
    const int n0 = blockIdx.x * 64;
    const int t = threadIdx.x, wave = t >> 6, lane = t & 63;
    const int wr = (wave >> 1) * 32, wc = (wave & 1) * 32;
    const int lr = lane & 15, kg = lane >> 4;
    const int sr = t >> 2, sc = (t & 3) * 16;
    const f16_t* arp;
    if constexpr (GATHER) arp = A + (long long)tok_of_slot[m0 + sr] * lda;
    else                  arp = A + (long long)(m0 + sr) * lda;
    const f16_t* brp = B + (long long)(n0 + sr) * ldb;

    f32x4 acc[2][2] = {};
    for (int k0 = 0; k0 < K; k0 += 64) {
        *reinterpret_cast<f16x8*>(&As[sr][sc])     = *reinterpret_cast<const f16x8*>(&arp[k0 + sc]);
        *reinterpret_cast<f16x8*>(&As[sr][sc + 8]) = *reinterpret_cast<const f16x8*>(&arp[k0 + sc + 8]);
        *reinterpret_cast<f16x8*>(&Bs[sr][sc])     = *reinterpret_cast<const f16x8*>(&brp[k0 + sc]);
        *reinterpret_cast<f16x8*>(&Bs[sr][sc + 8]) = *reinterpret_cast<const f16x8*>(&brp[k0 + sc + 8]);
        __syncthreads();
        #pragma unroll
        for (int c = 0; c < 2; c++) {
            f16x8 a0 = *reinterpret_cast<const f16x8*>(&As[wr + lr][c * 32 + kg * 8]);
            f16x8 a1 = *reinterpret_cast<const f16x8*>(&As[wr + 16 + lr][c * 32 + kg * 8]);
            f16x8 b0 = *reinterpret_cast<const f16x8*>(&Bs[wc + lr][c * 32 + kg * 8]);
            f16x8 b1 = *reinterpret_cast<const f16x8*>(&Bs[wc + 16 + lr][c * 32 + kg * 8]);
            acc[0][0] = __builtin_amdgcn_mfma_f32_16x16x32_f16(a0, b0, acc[0][0], 0, 0, 0);
            acc[0][1] = __builtin_amdgcn_mfma_f32_16x16x32_f16(a0, b1, acc[0][1], 0, 0, 0);
            acc[1][0] = __builtin_amdgcn_mfma_f32_16x16x32_f16(a1, b0, acc[1][0], 0, 0, 0);
            acc[1][1] = __builtin_amdgcn_mfma_f32_16x16x32_f16(a1, b1, acc[1][1], 0, 0, 0);
        }
        __syncthreads();
    }
    #pragma unroll
    for (int mi = 0; mi < 2; mi++)
        #pragma unroll
        for (int ni = 0; ni < 2; ni++)
            #pragma unroll
            for (int r = 0; r < 4; r++) {
                const int row = m0 + wr + mi * 16 + kg * 4 + r;
                const int col = n0 + wc + ni * 16 + lr;
                float v = acc[mi][ni][r] + bs[col];
                if constexpr (RELU) v = fmaxf(v, 0.f);
                if constexpr (OUTF16) ((f16_t*)Cv)[(long long)row * ldc + col] = (f16_t)v;
                else                  ((float*)Cv)[(long long)row * ldc + col] = v;
            }
}

// ================= V transpose: VT[z][d][s] from V16 [token][256] =================
// V16 elem addr = s*1024 + 64*z + d
__global__ __launch_bounds__(256) void vtrans_kernel(
    const f16_t* __restrict__ V16, f16_t* __restrict__ VT)
{
    __shared__ f16_t tile[32][33];
    const int z = blockIdx.z;
    const int s0 = blockIdx.x * 32, d0 = blockIdx.y * 32;
    const int tx = threadIdx.x & 31, ty = threadIdx.x >> 5;
    #pragma unroll
    for (int i = 0; i < 32; i += 8)
        tile[ty + i][tx] = V16[(long long)(s0 + ty + i) * 1024 + 64 * z + d0 + tx];
    __syncthreads();
    #pragma unroll
    for (int i = 0; i < 32; i += 8)
        VT[(long long)z * 131072 + (long long)(d0 + ty + i) * 2048 + s0 + tx] = tile[tx][ty + i];
}

// ================= flash attention, split-KV: block = (q-tile 64, z, chunk) ============
// chunk covers k in [c*512, (c+1)*512). Writes unnormalized Opart (f32) + per-row m,l.
__global__ __launch_bounds__(256) void flash_kernel(
    const f16_t* __restrict__ Q16, const f16_t* __restrict__ K16,
    const f16_t* __restrict__ VT, float* __restrict__ Opart,
    float* __restrict__ mlm, float* __restrict__ mll)
{
    __shared__ f16_t Ks[64][72];
    __shared__ f16_t VTs[64][72];
    __shared__ f16_t Ps[4][16][72];

    const int z = blockIdx.y;
    const int c = blockIdx.z;
    const int m0 = blockIdx.x * 64;          // slab q-row
    const int t = threadIdx.x, w = t >> 6, lane = t & 63;
    const int lr = lane & 15, kg = lane >> 4;
    const long long cbase = 64LL * z;

    // Q fragments, pre-scaled by 1/8 (exact pow2)
    f16x8 qf0, qf1;
    {
        const long long qrow = (long long)(m0 + w * 16 + lr) * 1024 + cbase;
        qf0 = *reinterpret_cast<const f16x8*>(&Q16[qrow + kg * 8]);
        qf1 = *reinterpret_cast<const f16x8*>(&Q16[qrow + 32 + kg * 8]);
        #pragma unroll
        for (int i = 0; i < 8; i++) { qf0[i] *= (f16_t)0.125f; qf1[i] *= (f16_t)0.125f; }
    }

    f32x4 oacc[4] = {};
    float mrun[4] = { -1e30f, -1e30f, -1e30f, -1e30f };
    float lrun[4] = {};

    const int sr = t >> 2, sc = (t & 3) * 16;
    const int nbeg = c * 512;
    for (int n0 = nbeg; n0 < nbeg + 512; n0 += 64) {
        // ---- stage K (rows=s) and VT (rows=d), both pure vector copies ----
        const long long krow = (long long)(n0 + sr) * 1024 + cbase;
        const long long vrow = (long long)z * 131072 + (long long)sr * 2048 + n0;
        *reinterpret_cast<f16x8*>(&Ks[sr][sc])      = *reinterpret_cast<const f16x8*>(&K16[krow + sc]);
        *reinterpret_cast<f16x8*>(&Ks[sr][sc + 8])  = *reinterpret_cast<const f16x8*>(&K16[krow + sc + 8]);
        *reinterpret_cast<f16x8*>(&VTs[sr][sc])     = *reinterpret_cast<const f16x8*>(&VT[vrow + sc]);
        *reinterpret_cast<f16x8*>(&VTs[sr][sc + 8]) = *reinterpret_cast<const f16x8*>(&VT[vrow + sc + 8]);
        __syncthreads();

        // ---- S = (Q/8) K^T ----
        float sv[4][4];
        #pragma unroll
        for (int nt = 0; nt < 4; nt++) {
            f32x4 acc = {};
            f16x8 b0 = *reinterpret_cast<const f16x8*>(&Ks[nt * 16 + lr][kg * 8]);
            f16x8 b1 = *reinterpret_cast<const f16x8*>(&Ks[nt * 16 + lr][32 + kg * 8]);
            acc = __builtin_amdgcn_mfma_f32_16x16x32_f16(qf0, b0, acc, 0, 0, 0);
            acc = __builtin_amdgcn_mfma_f32_16x16x32_f16(qf1, b1, acc, 0, 0, 0);
            #pragma unroll
            for (int r = 0; r < 4; r++) sv[nt][r] = acc[r];
        }

        // ---- online softmax (row = kg*4+r; reduce across 16-lane group) ----
        float mnew[4], alpha[4];
        #pragma unroll
        for (int r = 0; r < 4; r++) {
            float rm = fmaxf(fmaxf(sv[0][r], sv[1][r]), fmaxf(sv[2][r], sv[3][r]));
            rm = fmaxf(rm, __shfl_xor(rm, 1));
            rm = fmaxf(rm, __shfl_xor(rm, 2));
            rm = fmaxf(rm, __shfl_xor(rm, 4));
            rm = fmaxf(rm, __shfl_xor(rm, 8));
            mnew[r] = fmaxf(mrun[r], rm);
            alpha[r] = __expf(mrun[r] - mnew[r]);
            mrun[r] = mnew[r];
        }
        #pragma unroll
        for (int nt = 0; nt < 4; nt++)
            #pragma unroll
            for (int r = 0; r < 4; r++) sv[nt][r] = __expf(sv[nt][r] - mnew[r]);
        #pragma unroll
        for (int r = 0; r < 4; r++) {
            float rs = sv[0][r] + sv[1][r] + sv[2][r] + sv[3][r];
            rs += __shfl_xor(rs, 1);
            rs += __shfl_xor(rs, 2);
            rs += __shfl_xor(rs, 4);
            rs += __shfl_xor(rs, 8);
            lrun[r] = lrun[r] * alpha[r] + rs;
        }
        #pragma unroll
        for (int dt = 0; dt < 4; dt++)
            #pragma unroll
            for (int r = 0; r < 4; r++) oacc[dt][r] *= alpha[r];

        // ---- P: C-layout -> A-layout via per-wave LDS (same-wave) ----
        #pragma unroll
        for (int nt = 0; nt < 4; nt++)
            #pragma unroll
            for (int r = 0; r < 4; r++)
                Ps[w][kg * 4 + r][nt * 16 + lr] = (f16_t)sv[nt][r];

        f16x8 pa0 = *reinterpret_cast<const f16x8*>(&Ps[w][lr][kg * 8]);
        f16x8 pa1 = *reinterpret_cast<const f16x8*>(&Ps[w][lr][32 + kg * 8]);
        #pragma unroll
        for (int dt = 0; dt < 4; dt++) {
            f16x8 vb0 = *reinterpret_cast<const f16x8*>(&VTs[dt * 16 + lr][kg * 8]);
            f16x8 vb1 = *reinterpret_cast<const f16x8*>(&VTs[dt * 16 + lr][32 + kg * 8]);
            oacc[dt] = __builtin_amdgcn_mfma_f32_16x16x32_f16(pa0, vb0, oacc[dt], 0, 0, 0);
            oacc[dt] = __builtin_amdgcn_mfma_f32_16x16x32_f16(pa1, vb1, oacc[dt], 0, 0, 0);
        }
        __syncthreads();
    }

    // ---- write unnormalized partials + (m,l) ----
    float* op = Opart + (long long)c * 2097152;
    const long long orow0 = (long long)(m0 + w * 16) * 1024 + cbase;
    #pragma unroll
    for (int r = 0; r < 4; r++)
        #pragma unroll
        for (int dt = 0; dt < 4; dt++)
            op[orow0 + (long long)(kg * 4 + r) * 1024 + dt * 16 + lr] = oacc[dt][r];
    if (lr == 0) {
        const int b = z >> 2, h = z & 3;
        #pragma unroll
        for (int r = 0; r < 4; r++) {
            const int tok = (m0 + w * 16 + kg * 4 + r) * 4 + b;
            const long long idx = (long long)(c * 4 + h) * 8192 + tok;
            mlm[idx] = mrun[r];
            mll[idx] = lrun[r];
        }
    }
}

// ================= merge 4 split-KV chunks -> O16 f16 =================
__global__ __launch_bounds__(256) void merge_kernel(
    const float* __restrict__ Opart, const float* __restrict__ mlm,
    const float* __restrict__ mll, f16_t* __restrict__ O16)
{
    const int w = threadIdx.x >> 6, lane = threadIdx.x & 63;
    const int trow = blockIdx.x * 4 + w;
    const int h = lane >> 4;
    float m[4], l[4];
    #pragma unroll
    for (int c = 0; c < 4; c++) {
        m[c] = mlm[(long long)(c * 4 + h) * 8192 + trow];
        l[c] = mll[(long long)(c * 4 + h) * 8192 + trow];
    }
    float M = fmaxf(fmaxf(m[0], m[1]), fmaxf(m[2], m[3]));
    float wv[4], L = 0.f;
    #pragma unroll
    for (int c = 0; c < 4; c++) { wv[c] = __expf(m[c] - M); L += wv[c] * l[c]; }
    const float inv = 1.f / L;
    const long long base = (long long)trow * 256 + lane * 4;
    float4 acc = make_float4(0.f, 0.f, 0.f, 0.f);
    #pragma unroll
    for (int c = 0; c < 4; c++) {
        float4 v = *reinterpret_cast<const float4*>(&Opart[(long long)c * 2097152 + base]);
        acc.x += wv[c] * v.x; acc.y += wv[c] * v.y;
        acc.z += wv[c] * v.z; acc.w += wv[c] * v.w;
    }
    f16_t o[4] = { (f16_t)(acc.x * inv), (f16_t)(acc.y * inv),
                   (f16_t)(acc.z * inv), (f16_t)(acc.w * inv) };
    *reinterpret_cast<ulong1*>(&O16[base]) = *reinterpret_cast<ulong1*>(o);
}

// ================= prep: weight transpose-convert, activation convert =================
__global__ __launch_bounds__(256) void wtrans_kernel(
    const float* __restrict__ in, f16_t* __restrict__ out, int R, int C)
{
    __shared__ float tile[32][33];
    const long long zoff = (long long)blockIdx.z * R * C;
    const int r0 = blockIdx.y * 32, c0 = blockIdx.x * 32;
    const int tx = threadIdx.x & 31, ty = threadIdx.x >> 5;
    #pragma unroll
    for (int i = 0; i < 32; i += 8)
        tile[ty + i][tx] = in[zoff + (long long)(r0 + ty + i) * C + c0 + tx];
    __syncthreads();
    #pragma unroll
    for (int i = 0; i < 32; i += 8)
        out[zoff + (long long)(c0 + ty + i) * R + r0 + tx] = (f16_t)tile[tx][ty + i];
}

__global__ __launch_bounds__(256) void cvt16_kernel(
    const float* __restrict__ in, f16_t* __restrict__ out)
{
    const long long i = ((long long)blockIdx.x * 256 + threadIdx.x) * 4;
    float4 v = *reinterpret_cast<const float4*>(&in[i]);
    f16_t o[4] = { (f16_t)v.x, (f16_t)v.y, (f16_t)v.z, (f16_t)v.w };
    *reinterpret_cast<ulong1*>(&out[i]) = *reinterpret_cast<ulong1*>(o);
}

// ================= LN(in1+in2)*g+b -> f32 (+optional f16) =================
__global__ __launch_bounds__(256) void ln_kernel(
    const float* __restrict__ in1, const float* __restrict__ in2,
    const float* __restrict__ gamma, const float* __restrict__ beta,
    float* __restrict__ out, f16_t* __restrict__ out16)
{
    const int wave = threadIdx.x >> 6, lane = threadIdx.x & 63;
    const long long row = (long long)blockIdx.x * 4 + wave;
    const long long base = row * 256 + lane * 4;
    float4 a = *reinterpret_cast<const float4*>(&in1[base]);
    float4 b = *reinterpret_cast<const float4*>(&in2[base]);
    float x[4] = { a.x + b.x, a.y + b.y, a.z + b.z, a.w + b.w };
    float s = x[0] + x[1] + x[2] + x[3];
    float s2 = x[0]*x[0] + x[1]*x[1] + x[2]*x[2] + x[3]*x[3];
    #pragma unroll
    for (int o = 32; o; o >>= 1) { s += __shfl_xor(s, o); s2 += __shfl_xor(s2, o); }
    const float mean = s * (1.f / 256.f);
    const float var = s2 * (1.f / 256.f) - mean * mean;
    const float rstd = rsqrtf(var + 1e-5f);
    float4 g = *reinterpret_cast<const float4*>(&gamma[lane * 4]);
    float4 bb = *reinterpret_cast<const float4*>(&beta[lane * 4]);
    const float* gf = reinterpret_cast<const float*>(&g);
    const float* bf = reinterpret_cast<const float*>(&bb);
    float y[4];
    #pragma unroll
    for (int i = 0; i < 4; i++) y[i] = (x[i] - mean) * rstd * gf[i] + bf[i];
    *reinterpret_cast<float4*>(&out[base]) = make_float4(y[0], y[1], y[2], y[3]);
    if (out16) {
        f16_t o[4] = { (f16_t)y[0], (f16_t)y[1], (f16_t)y[2], (f16_t)y[3] };
        *reinterpret_cast<ulong1*>(&out16[base]) = *reinterpret_cast<ulong1*>(o);
    }
}

// ================= gating (1 thread/token, hierarchical) =================
__global__ __launch_bounds__(256) void gating_kernel(
    const float* __restrict__ X, const float* __restrict__ Wg, const float* __restrict__ bg,
    int* __restrict__ gcount, float* __restrict__ counts,
    int* __restrict__ pos_of_tok, int* __restrict__ exp_of_tok,
    float* __restrict__ gate_of_tok)
{
    __shared__ float WgL[2048];
    __shared__ float cpart[8];
    __shared__ int lcnt[8];
    __shared__ int lbase[8];
    const int t = threadIdx.x;
    for (int i = t; i < 2048; i += 256) WgL[i] = Wg[i];
    if (t < 8) { cpart[t] = 0.f; lcnt[t] = 0; }
    __syncthreads();

    const int tok = blockIdx.x * 256 + t;
    const float* xr = X + (long long)tok * 256;
    float acc[8] = {};
    for (int k = 0; k < 256; k += 4) {
        float4 xv = *reinterpret_cast<const float4*>(xr + k);
        const float* xf = reinterpret_cast<const float*>(&xv);
        #pragma unroll
        for (int i = 0; i < 4; i++) {
            const float xi = xf[i];
            const float* wrow = &WgL[(k + i) * 8];
            #pragma unroll
            for (int e = 0; e < 8; e++) acc[e] += xi * wrow[e];
        }
    }
    float p[8]; float mx = -1e30f;
    #pragma unroll
    for (int e = 0; e < 8; e++) { p[e] = acc[e] + bg[e]; mx = fmaxf(mx, p[e]); }
    float se = 0.f;
    #pragma unroll
    for (int e = 0; e < 8; e++) { p[e] = __expf(p[e] - mx); se += p[e]; }
    const float inv = 1.f / se;
    #pragma unroll
    for (int e = 0; e < 8; e++) { p[e] *= inv; atomicAdd(&cpart[e], p[e]); }

    int i1 = 0;
    #pragma unroll
    for (int e = 1; e < 8; e++) if (p[e] > p[i1]) i1 = e;
    int i2 = (i1 == 0) ? 1 : 0;
    #pragma unroll
    for (int e = 0; e < 8; e++) if (e != i1 && p[e] > p[i2]) i2 = e;
    const float gs = 1.f / (p[i1] + p[i2]);

    const int p1 = atomicAdd(&lcnt[i1], 1);
    const int p2 = atomicAdd(&lcnt[i2], 1);
    __syncthreads();
    if (t < 8) {
        lbase[t] = atomicAdd(&gcount[t], lcnt[t]);
        atomicAdd(&counts[t], cpart[t]);
    }
    __syncthreads();
    pos_of_tok[2 * tok]     = lbase[i1] + p1;
    pos_of_tok[2 * tok + 1] = lbase[i2] + p2;
    exp_of_tok[2 * tok]     = i1;
    exp_of_tok[2 * tok + 1] = i2;
    gate_of_tok[2 * tok]     = p[i1] * gs;
    gate_of_tok[2 * tok + 1] = p[i2] * gs;
}

__global__ void finalize_kernel(const int* __restrict__ gcount, int* __restrict__ ebase)
{
    if (threadIdx.x == 0) {
        int b = 0;
        for (int e = 0; e < 8; e++) { ebase[e] = b; b += (gcount[e] + 63) & ~63; }
        ebase[8] = b;
    }
}

__global__ __launch_bounds__(256) void scatter_kernel(
    const int* __restrict__ pos_of_tok, const int* __restrict__ exp_of_tok,
    const int* __restrict__ ebase, int* __restrict__ tok_of_slot)
{
    const int i = blockIdx.x * 256 + threadIdx.x;
    const int e = exp_of_tok[i];
    tok_of_slot[ebase[e] + pos_of_tok[i]] = i >> 1;
}

// out = LN(gv1*Ys[s1] + gv2*Ys[s2] + X1), optional f16 copy
__global__ __launch_bounds__(256) void moe_combine_ln_kernel(
    const float* __restrict__ Ys, const float* __restrict__ X1,
    const int* __restrict__ pos_of_tok, const int* __restrict__ exp_of_tok,
    const float* __restrict__ gate_of_tok, const int* __restrict__ ebase,
    const float* __restrict__ gamma, const float* __restrict__ beta,
    float* __restrict__ out, f16_t* __restrict__ out16)
{
    const int wave = threadIdx.x >> 6, lane = threadIdx.x & 63;
    const long long tok = (long long)blockIdx.x * 4 + wave;
    const int e1 = exp_of_tok[2 * tok], e2 = exp_of_tok[2 * tok + 1];
    const long long s1 = ebase[e1] + pos_of_tok[2 * tok];
    const long long s2 = ebase[e2] + pos_of_tok[2 * tok + 1];
    const float gv1 = gate_of_tok[2 * tok], gv2 = gate_of_tok[2 * tok + 1];
    const long long base = tok * 256 + lane * 4;
    float4 y1 = *reinterpret_cast<const float4*>(&Ys[s1 * 256 + lane * 4]);
    float4 y2 = *reinterpret_cast<const float4*>(&Ys[s2 * 256 + lane * 4]);
    float4 xv = *reinterpret_cast<const float4*>(&X1[base]);
    float x[4] = { gv1 * y1.x + gv2 * y2.x + xv.x,
                   gv1 * y1.y + gv2 * y2.y + xv.y,
                   gv1 * y1.z + gv2 * y2.z + xv.z,
                   gv1 * y1.w + gv2 * y2.w + xv.w };
    float s = x[0] + x[1] + x[2] + x[3];
    float s2v = x[0]*x[0] + x[1]*x[1] + x[2]*x[2] + x[3]*x[3];
    #pragma unroll
    for (int o = 32; o; o >>= 1) { s += __shfl_xor(s, o); s2v += __shfl_xor(s2v, o); }
    const float mean = s * (1.f / 256.f);
    const float var = s2v * (1.f / 256.f) - mean * mean;
    const float rstd = rsqrtf(var + 1e-5f);
    float4 g = *reinterpret_cast<const float4*>(&gamma[lane * 4]);
    float4 bb = *reinterpret_cast<const float4*>(&beta[lane * 4]);
    const float* gf = reinterpret_cast<const float*>(&g);
    const float* bf = reinterpret_cast<const float*>(&bb);
    float y[4];
    #pragma unroll
    for (int i = 0; i < 4; i++) y[i] = (x[i] - mean) * rstd * gf[i] + bf[i];
    *reinterpret_cast<float4*>(&out[base]) = make_float4(y[0], y[1], y[2], y[3]);
    if (out16) {
        f16_t o[4] = { (f16_t)y[0], (f16_t)y[1], (f16_t)y[2], (f16_t)y[3] };
        *reinterpret_cast<ulong1*>(&out16[base]) = *reinterpret_cast<ulong1*>(o);
    }
}

__global__ void aux_kernel(const float* __restrict__ counts, float* __restrict__ out)
{
    if (threadIdx.x == 0) {
        float aux = 0.f;
        for (int pzz = 0; pzz < 2; pzz++) {
            const float* c = counts + pzz * 8;
            float tot = 0.f;
            for (int e = 0; e < 8; e++) tot += c[e];
            float s = 0.f;
            for (int e = 0; e < 8; e++) s += (c[e] / tot) * (c[e] * (1.f / 8192.f));
            aux += 8.f * s;
        }
        out[0] = 0.01f * aux;
    }
}

extern "C" void kernel_launch(void* const* d_in, const int* in_sizes, int n_in,
                              void* d_out, int out_size, void* d_ws, size_t ws_size,
                              hipStream_t stream)
{
    const float* Xc  = (const float*)d_in[0];
    const float* Xt  = (const float*)d_in[1];
    const float* Wq  = (const float*)d_in[2];
    const float* Wk  = (const float*)d_in[3];
    const float* Wv  = (const float*)d_in[4];
    const float* bq  = (const float*)d_in[5];
    const float* bk  = (const float*)d_in[6];
    const float* bv  = (const float*)d_in[7];
    const float* Wo  = (const float*)d_in[8];
    const float* bo  = (const float*)d_in[9];
    const float* Wg  = (const float*)d_in[10];
    const float* bg  = (const float*)d_in[11];
    const float* W1  = (const float*)d_in[12];
    const float* b1  = (const float*)d_in[13];
    const float* W2  = (const float*)d_in[14];
    const float* b2  = (const float*)d_in[15];
    const float* g_c1 = (const float*)d_in[16];
    const float* b_c1 = (const float*)d_in[17];
    const float* g_c2 = (const float*)d_in[18];
    const float* b_c2 = (const float*)d_in[19];
    const float* g_t1 = (const float*)d_in[20];
    const float* b_t1 = (const float*)d_in[21];
    const float* g_t2 = (const float*)d_in[22];
    const float* b_t2 = (const float*)d_in[23];

    const long long NTOK = 2097152;          // 8192 tokens * 256
    const int SLOT_MAX = 16896;              // 264 * 64
    float* dout = (float*)d_out;             // fp32: xc | xt | aux
    float* xcout = dout;
    float* xtout = dout + NTOK;

    float* ws = (float*)d_ws;
    float* P1 = ws;
    float* X1 = P1 + NTOK;
    float* Ys = X1 + NTOK;                               // SLOT_MAX x 256
    float* counts      = Ys + (long long)SLOT_MAX * 256; // 16
    float* gate_of_tok = counts + 16;                    // 16384
    float* mlm = gate_of_tok + 16384;                    // 4*4*8192
    float* mll = mlm + 131072;                           // 4*4*8192
    int* gcount      = (int*)(mll + 131072);             // 16
    int* ebase       = gcount + 16;                      // 16
    int* pos_of_tok  = ebase + 16;                       // 16384
    int* exp_of_tok  = pos_of_tok + 16384;               // 16384
    int* tok_of_slot = exp_of_tok + 16384;               // SLOT_MAX
    f16_t* h16 = (f16_t*)(tok_of_slot + SLOT_MAX);
    f16_t* Xc16 = h16;
    f16_t* Xt16 = Xc16 + NTOK;
    f16_t* xc16 = Xt16 + NTOK;
    f16_t* Q16  = xc16 + NTOK;
    f16_t* K16  = Q16 + NTOK;
    f16_t* V16  = K16 + NTOK;
    f16_t* O16  = V16 + NTOK;
    f16_t* X116 = O16 + NTOK;
    f16_t* VT   = X116 + NTOK;                           // 16 z x 64 d x 2048 s
    f16_t* Hs16 = VT + NTOK;                             // SLOT_MAX x 1024 (MoE phase)
    f16_t* WqT  = Hs16 + (long long)SLOT_MAX * 1024;
    f16_t* WkT  = WqT + 65536;
    f16_t* WvT  = WkT + 65536;
    f16_t* WoT  = WvT + 65536;
    f16_t* W1T  = WoT + 65536;                           // 8 x 1024 x 256
    f16_t* W2T  = W1T + 2097152;                         // 8 x 256 x 1024
    float* Opart = (float*)Hs16;                         // alias: attention phase only (4*NTOK f32 = 32MB <= 33MB)

    hipMemsetAsync(counts, 0, 16 * sizeof(float), stream);
    hipMemsetAsync(gcount, 0, 16 * sizeof(int), stream);

    // ---- prep ----
    cvt16_kernel<<<2048, 256, 0, stream>>>(Xc, Xc16);
    cvt16_kernel<<<2048, 256, 0, stream>>>(Xt, Xt16);
    wtrans_kernel<<<dim3(8, 8, 1), 256, 0, stream>>>(Wq, WqT, 256, 256);
    wtrans_kernel<<<dim3(8, 8, 1), 256, 0, stream>>>(Wk, WkT, 256, 256);
    wtrans_kernel<<<dim3(8, 8, 1), 256, 0, stream>>>(Wv, WvT, 256, 256);
    wtrans_kernel<<<dim3(8, 8, 1), 256, 0, stream>>>(Wo, WoT, 256, 256);
    wtrans_kernel<<<dim3(32, 8, 8), 256, 0, stream>>>(W1, W1T, 256, 1024);
    wtrans_kernel<<<dim3(8, 32, 8), 256, 0, stream>>>(W2, W2T, 1024, 256);

    for (int pass = 0; pass < 2; pass++) {
        const float*  xq    = pass ? Xt   : Xc;
        const f16_t*  xq16  = pass ? Xt16 : Xc16;
        const f16_t*  xkv16 = pass ? xc16 : Xc16;
        const float* g1  = pass ? g_t1 : g_c1;
        const float* be1 = pass ? b_t1 : b_c1;
        const float* g2  = pass ? g_t2 : g_c2;
        const float* be2 = pass ? b_t2 : b_c2;
        float* cnt = counts + pass * 8;
        int* gcnt  = gcount + pass * 8;
        float* oln = pass ? xtout : xcout;
        f16_t* oln16 = pass ? nullptr : xc16;

        // Q/K/V projections in one dispatch
        qkv_kernel<<<dim3(4, 128, 3), 256, 0, stream>>>(
            xq16, xkv16, WqT, WkT, WvT, bq, bk, bv, Q16, K16, V16);

        // V -> VT[z][d][s], then split-KV flash + merge
        vtrans_kernel<<<dim3(64, 2, 16), 256, 0, stream>>>(V16, VT);
        flash_kernel<<<dim3(32, 16, 4), 256, 0, stream>>>(Q16, K16, VT, Opart, mlm, mll);
        merge_kernel<<<2048, 256, 0, stream>>>(Opart, mlm, mll, O16);

        // output projection + LN1 (dual f32/f16)
        gemm16_kernel<true,false><<<dim3(4, 128), 256, 0, stream>>>(
            O16, WoT, P1, bo, 8192, 256, 256, 256, 256, 256);
        ln_kernel<<<2048, 256, 0, stream>>>(P1, xq, g1, be1, X1, X116);

        // ---- sparse top-2 MoE ----
        hipMemsetAsync(tok_of_slot, 0, SLOT_MAX * sizeof(int), stream);
        gating_kernel<<<32, 256, 0, stream>>>(X1, Wg, bg, gcnt, cnt,
                                              pos_of_tok, exp_of_tok, gate_of_tok);
        finalize_kernel<<<1, 64, 0, stream>>>(gcnt, ebase);
        scatter_kernel<<<64, 256, 0, stream>>>(pos_of_tok, exp_of_tok, ebase, tok_of_slot);
        moe_gemm16_kernel<true,true,true><<<dim3(16, 264), 256, 0, stream>>>(
            X116, tok_of_slot, W1T, b1, Hs16, ebase,
            1024, 256, 256, 256, 1024, 262144, 1024);
        moe_gemm16_kernel<false,false,false><<<dim3(4, 264), 256, 0, stream>>>(
            Hs16, nullptr, W2T, b2, Ys, ebase,
            256, 1024, 1024, 1024, 256, 262144, 256);
        moe_combine_ln_kernel<<<2048, 256, 0, stream>>>(
            Ys, X1, pos_of_tok, exp_of_tok, gate_of_tok, ebase, g2, be2, oln, oln16);
    }

    aux_kernel<<<1, 64, 0, stream>>>(counts, dout + 2 * NTOK);
}

// Round 6
// 580.940 us; speedup vs baseline: 7.6305x; 1.0187x over previous
//
#include <hip/hip_runtime.h>
#include <hip/hip_bf16.h>

typedef _Float16 f16_t;
typedef _Float16 f16x4v __attribute__((ext_vector_type(4)));
typedef _Float16 f16x8 __attribute__((ext_vector_type(8)));
typedef float f32x4 __attribute__((ext_vector_type(4)));

// ================= generic f16 GEMM: C[M,N] = A[M,K] @ B^T (B stored [N][K]) ==========
template<bool BIAS, bool OUTF16>
__global__ __launch_bounds__(256) void gemm16_kernel(
    const f16_t* __restrict__ A, const f16_t* __restrict__ B, void* __restrict__ Cv,
    const float* __restrict__ bias, int M, int N, int K, int lda, int ldb, int ldc)
{
    __shared__ f16_t As[64][72];
    __shared__ f16_t Bs[64][72];
    const int m0 = blockIdx.y * 64, n0 = blockIdx.x * 64;
    const int t = threadIdx.x, wave = t >> 6, lane = t & 63;
    const int wr = (wave >> 1) * 32, wc = (wave & 1) * 32;
    const int lr = lane & 15, kg = lane >> 4;
    const int sr = t >> 2, sc = (t & 3) * 16;
    const f16_t* arp = A + (long long)(m0 + sr) * lda;
    const f16_t* brp = B + (long long)(n0 + sr) * ldb;

    f32x4 acc[2][2] = {};
    for (int k0 = 0; k0 < K; k0 += 64) {
        *reinterpret_cast<f16x8*>(&As[sr][sc])     = *reinterpret_cast<const f16x8*>(&arp[k0 + sc]);
        *reinterpret_cast<f16x8*>(&As[sr][sc + 8]) = *reinterpret_cast<const f16x8*>(&arp[k0 + sc + 8]);
        *reinterpret_cast<f16x8*>(&Bs[sr][sc])     = *reinterpret_cast<const f16x8*>(&brp[k0 + sc]);
        *reinterpret_cast<f16x8*>(&Bs[sr][sc + 8]) = *reinterpret_cast<const f16x8*>(&brp[k0 + sc + 8]);
        __syncthreads();
        #pragma unroll
        for (int c = 0; c < 2; c++) {
            f16x8 a0 = *reinterpret_cast<const f16x8*>(&As[wr + lr][c * 32 + kg * 8]);
            f16x8 a1 = *reinterpret_cast<const f16x8*>(&As[wr + 16 + lr][c * 32 + kg * 8]);
            f16x8 b0 = *reinterpret_cast<const f16x8*>(&Bs[wc + lr][c * 32 + kg * 8]);
            f16x8 b1 = *reinterpret_cast<const f16x8*>(&Bs[wc + 16 + lr][c * 32 + kg * 8]);
            acc[0][0] = __builtin_amdgcn_mfma_f32_16x16x32_f16(a0, b0, acc[0][0], 0, 0, 0);
            acc[0][1] = __builtin_amdgcn_mfma_f32_16x16x32_f16(a0, b1, acc[0][1], 0, 0, 0);
            acc[1][0] = __builtin_amdgcn_mfma_f32_16x16x32_f16(a1, b0, acc[1][0], 0, 0, 0);
            acc[1][1] = __builtin_amdgcn_mfma_f32_16x16x32_f16(a1, b1, acc[1][1], 0, 0, 0);
        }
        __syncthreads();
    }
    #pragma unroll
    for (int mi = 0; mi < 2; mi++)
        #pragma unroll
        for (int ni = 0; ni < 2; ni++)
            #pragma unroll
            for (int r = 0; r < 4; r++) {
                const int row = m0 + wr + mi * 16 + kg * 4 + r;
                const int col = n0 + wc + ni * 16 + lr;
                float v = acc[mi][ni][r];
                if constexpr (BIAS) v += bias[col];
                if constexpr (OUTF16) ((f16_t*)Cv)[(long long)row * ldc + col] = (f16_t)v;
                else                  ((float*)Cv)[(long long)row * ldc + col] = v;
            }
}

// ================= fused Q/K/V projection: blockIdx.z picks {W,bias,out,A} ============
__global__ __launch_bounds__(256) void qkv_kernel(
    const f16_t* __restrict__ Aq, const f16_t* __restrict__ Akv,
    const f16_t* __restrict__ B0, const f16_t* __restrict__ B1, const f16_t* __restrict__ B2,
    const float* __restrict__ bi0, const float* __restrict__ bi1, const float* __restrict__ bi2,
    f16_t* __restrict__ C0, f16_t* __restrict__ C1, f16_t* __restrict__ C2)
{
    const int zz = blockIdx.z;
    const f16_t* A = (zz == 0) ? Aq : Akv;
    const f16_t* B = (zz == 0) ? B0 : (zz == 1 ? B1 : B2);
    const float* bias = (zz == 0) ? bi0 : (zz == 1 ? bi1 : bi2);
    f16_t* C = (zz == 0) ? C0 : (zz == 1 ? C1 : C2);

    __shared__ f16_t As[64][72];
    __shared__ f16_t Bs[64][72];
    const int m0 = blockIdx.y * 64, n0 = blockIdx.x * 64;
    const int t = threadIdx.x, wave = t >> 6, lane = t & 63;
    const int wr = (wave >> 1) * 32, wc = (wave & 1) * 32;
    const int lr = lane & 15, kg = lane >> 4;
    const int sr = t >> 2, sc = (t & 3) * 16;
    const f16_t* arp = A + (long long)(m0 + sr) * 256;
    const f16_t* brp = B + (long long)(n0 + sr) * 256;

    f32x4 acc[2][2] = {};
    for (int k0 = 0; k0 < 256; k0 += 64) {
        *reinterpret_cast<f16x8*>(&As[sr][sc])     = *reinterpret_cast<const f16x8*>(&arp[k0 + sc]);
        *reinterpret_cast<f16x8*>(&As[sr][sc + 8]) = *reinterpret_cast<const f16x8*>(&arp[k0 + sc + 8]);
        *reinterpret_cast<f16x8*>(&Bs[sr][sc])     = *reinterpret_cast<const f16x8*>(&brp[k0 + sc]);
        *reinterpret_cast<f16x8*>(&Bs[sr][sc + 8]) = *reinterpret_cast<const f16x8*>(&brp[k0 + sc + 8]);
        __syncthreads();
        #pragma unroll
        for (int c = 0; c < 2; c++) {
            f16x8 a0 = *reinterpret_cast<const f16x8*>(&As[wr + lr][c * 32 + kg * 8]);
            f16x8 a1 = *reinterpret_cast<const f16x8*>(&As[wr + 16 + lr][c * 32 + kg * 8]);
            f16x8 b0 = *reinterpret_cast<const f16x8*>(&Bs[wc + lr][c * 32 + kg * 8]);
            f16x8 b1 = *reinterpret_cast<const f16x8*>(&Bs[wc + 16 + lr][c * 32 + kg * 8]);
            acc[0][0] = __builtin_amdgcn_mfma_f32_16x16x32_f16(a0, b0, acc[0][0], 0, 0, 0);
            acc[0][1] = __builtin_amdgcn_mfma_f32_16x16x32_f16(a0, b1, acc[0][1], 0, 0, 0);
            acc[1][0] = __builtin_amdgcn_mfma_f32_16x16x32_f16(a1, b0, acc[1][0], 0, 0, 0);
            acc[1][1] = __builtin_amdgcn_mfma_f32_16x16x32_f16(a1, b1, acc[1][1], 0, 0, 0);
        }
        __syncthreads();
    }
    #pragma unroll
    for (int mi = 0; mi < 2; mi++)
        #pragma unroll
        for (int ni = 0; ni < 2; ni++)
            #pragma unroll
            for (int r = 0; r < 4; r++) {
                const int row = m0 + wr + mi * 16 + kg * 4 + r;
                const int col = n0 + wc + ni * 16 + lr;
                C[(long long)row * 256 + col] = (f16_t)(acc[mi][ni][r] + bias[col]);
            }
}

// ================= MoE f16 GEMM (slot-compacted; expert from block row) =================
template<bool GATHER, bool RELU, bool OUTF16>
__global__ __launch_bounds__(256) void moe_gemm16_kernel(
    const f16_t* __restrict__ A, const int* __restrict__ tok_of_slot,
    const f16_t* __restrict__ W, const float* __restrict__ bias,
    void* __restrict__ Cv, const int* __restrict__ ebase,
    int N, int K, int lda, int ldb, int ldc, int wstride, int bstride)
{
    const int m0 = blockIdx.y * 64;
    if (m0 >= ebase[8]) return;
    int e = 0;
    #pragma unroll
    for (int i = 1; i < 8; i++) if (m0 >= ebase[i]) e = i;
    const f16_t* __restrict__ B = W + (long long)e * wstride;
    const float* __restrict__ bs = bias + e * bstride;

    __shared__ f16_t As[64][72];
    __shared__ f16_t Bs[64][72];
    const int n0 = blockIdx.x * 64;
    const int t = threadIdx.x, wave = t >> 6, lane = t & 63;
    const int wr = (wave >> 1) * 32, wc = (wave & 1) * 32;
    const int lr = lane & 15, kg = lane >> 4;
    const int sr = t >> 2, sc = (t & 3) * 16;
    const f16_t* arp;
    if constexpr (GATHER) arp = A + (long long)(tok_of_slot[m0 + sr] & 8191) * lda;  // clamp: pad slots hold poison
    else                  arp = A + (long long)(m0 + sr) * lda;
    const f16_t* brp = B + (long long)(n0 + sr) * ldb;

    f32x4 acc[2][2] = {};
    for (int k0 = 0; k0 < K; k0 += 64) {
        *reinterpret_cast<f16x8*>(&As[sr][sc])     = *reinterpret_cast<const f16x8*>(&arp[k0 + sc]);
        *reinterpret_cast<f16x8*>(&As[sr][sc + 8]) = *reinterpret_cast<const f16x8*>(&arp[k0 + sc + 8]);
        *reinterpret_cast<f16x8*>(&Bs[sr][sc])     = *reinterpret_cast<const f16x8*>(&brp[k0 + sc]);
        *reinterpret_cast<f16x8*>(&Bs[sr][sc + 8]) = *reinterpret_cast<const f16x8*>(&brp[k0 + sc + 8]);
        __syncthreads();
        #pragma unroll
        for (int c = 0; c < 2; c++) {
            f16x8 a0 = *reinterpret_cast<const f16x8*>(&As[wr + lr][c * 32 + kg * 8]);
            f16x8 a1 = *reinterpret_cast<const f16x8*>(&As[wr + 16 + lr][c * 32 + kg * 8]);
            f16x8 b0 = *reinterpret_cast<const f16x8*>(&Bs[wc + lr][c * 32 + kg * 8]);
            f16x8 b1 = *reinterpret_cast<const f16x8*>(&Bs[wc + 16 + lr][c * 32 + kg * 8]);
            acc[0][0] = __builtin_amdgcn_mfma_f32_16x16x32_f16(a0, b0, acc[0][0], 0, 0, 0);
            acc[0][1] = __builtin_amdgcn_mfma_f32_16x16x32_f16(a0, b1, acc[0][1], 0, 0, 0);
            acc[1][0] = __builtin_amdgcn_mfma_f32_16x16x32_f16(a1, b0, acc[1][0], 0, 0, 0);
            acc[1][1] = __builtin_amdgcn_mfma_f32_16x16x32_f16(a1, b1, acc[1][1], 0, 0, 0);
        }
        __syncthreads();
    }
    #pragma unroll
    for (int mi = 0; mi < 2; mi++)
        #pragma unroll
        for (int ni = 0; ni < 2; ni++)
            #pragma unroll
            for (int r = 0; r < 4; r++) {
                const int row = m0 + wr + mi * 16 + kg * 4 + r;
                const int col = n0 + wc + ni * 16 + lr;
                float v = acc[mi][ni][r] + bs[col];
                if constexpr (RELU) v = fmaxf(v, 0.f);
                if constexpr (OUTF16) ((f16_t*)Cv)[(long long)row * ldc + col] = (f16_t)v;
                else                  ((float*)Cv)[(long long)row * ldc + col] = v;
            }
}

// ================= V transpose: VT[z][d][s] from V16 [token][256] =================
__global__ __launch_bounds__(256) void vtrans_kernel(
    const f16_t* __restrict__ V16, f16_t* __restrict__ VT)
{
    __shared__ f16_t tile[32][33];
    const int z = blockIdx.z;
    const int s0 = blockIdx.x * 32, d0 = blockIdx.y * 32;
    const int tx = threadIdx.x & 31, ty = threadIdx.x >> 5;
    #pragma unroll
    for (int i = 0; i < 32; i += 8)
        tile[ty + i][tx] = V16[(long long)(s0 + ty + i) * 1024 + 64 * z + d0 + tx];
    __syncthreads();
    #pragma unroll
    for (int i = 0; i < 32; i += 8)
        VT[(long long)z * 131072 + (long long)(d0 + ty + i) * 2048 + s0 + tx] = tile[tx][ty + i];
}

// ================= flash attention, split-KV; K/V time-share one LDS buffer ============
// chunk c covers k in [c*512, (c+1)*512). Writes unnormalized Opart (f16) + per-row m,l.
__global__ __launch_bounds__(256, 6) void flash_kernel(
    const f16_t* __restrict__ Q16, const f16_t* __restrict__ K16,
    const f16_t* __restrict__ VT, f16_t* __restrict__ Opart,
    float* __restrict__ mlm, float* __restrict__ mll)
{
    __shared__ f16_t KVs[64][72];      // K tile, then V^T tile (time-shared)
    __shared__ f16_t Ps[4][16][72];

    const int z = blockIdx.y;
    const int c = blockIdx.z;
    const int m0 = blockIdx.x * 64;
    const int t = threadIdx.x, w = t >> 6, lane = t & 63;
    const int lr = lane & 15, kg = lane >> 4;
    const long long cbase = 64LL * z;

    // Q fragments, pre-scaled by 1/8 (exact pow2)
    f16x8 qf0, qf1;
    {
        const long long qrow = (long long)(m0 + w * 16 + lr) * 1024 + cbase;
        qf0 = *reinterpret_cast<const f16x8*>(&Q16[qrow + kg * 8]);
        qf1 = *reinterpret_cast<const f16x8*>(&Q16[qrow + 32 + kg * 8]);
        #pragma unroll
        for (int i = 0; i < 8; i++) { qf0[i] *= (f16_t)0.125f; qf1[i] *= (f16_t)0.125f; }
    }

    f32x4 oacc[4] = {};
    float mrun[4] = { -1e30f, -1e30f, -1e30f, -1e30f };
    float lrun[4] = {};

    const int sr = t >> 2, sc = (t & 3) * 16;
    const int nbeg = c * 512;
    for (int n0 = nbeg; n0 < nbeg + 512; n0 += 64) {
        // ---- stage K ----
        const long long krow = (long long)(n0 + sr) * 1024 + cbase;
        *reinterpret_cast<f16x8*>(&KVs[sr][sc])     = *reinterpret_cast<const f16x8*>(&K16[krow + sc]);
        *reinterpret_cast<f16x8*>(&KVs[sr][sc + 8]) = *reinterpret_cast<const f16x8*>(&K16[krow + sc + 8]);
        __syncthreads();

        // ---- S = (Q/8) K^T ----
        float sv[4][4];
        #pragma unroll
        for (int nt = 0; nt < 4; nt++) {
            f32x4 acc = {};
            f16x8 b0 = *reinterpret_cast<const f16x8*>(&KVs[nt * 16 + lr][kg * 8]);
            f16x8 b1 = *reinterpret_cast<const f16x8*>(&KVs[nt * 16 + lr][32 + kg * 8]);
            acc = __builtin_amdgcn_mfma_f32_16x16x32_f16(qf0, b0, acc, 0, 0, 0);
            acc = __builtin_amdgcn_mfma_f32_16x16x32_f16(qf1, b1, acc, 0, 0, 0);
            #pragma unroll
            for (int r = 0; r < 4; r++) sv[nt][r] = acc[r];
        }

        // ---- online softmax (row = kg*4+r; reduce across 16-lane group) ----
        float mnew[4], alpha[4];
        #pragma unroll
        for (int r = 0; r < 4; r++) {
            float rm = fmaxf(fmaxf(sv[0][r], sv[1][r]), fmaxf(sv[2][r], sv[3][r]));
            rm = fmaxf(rm, __shfl_xor(rm, 1));
            rm = fmaxf(rm, __shfl_xor(rm, 2));
            rm = fmaxf(rm, __shfl_xor(rm, 4));
            rm = fmaxf(rm, __shfl_xor(rm, 8));
            mnew[r] = fmaxf(mrun[r], rm);
            alpha[r] = __expf(mrun[r] - mnew[r]);
            mrun[r] = mnew[r];
        }
        #pragma unroll
        for (int nt = 0; nt < 4; nt++)
            #pragma unroll
            for (int r = 0; r < 4; r++) sv[nt][r] = __expf(sv[nt][r] - mnew[r]);
        #pragma unroll
        for (int r = 0; r < 4; r++) {
            float rs = sv[0][r] + sv[1][r] + sv[2][r] + sv[3][r];
            rs += __shfl_xor(rs, 1);
            rs += __shfl_xor(rs, 2);
            rs += __shfl_xor(rs, 4);
            rs += __shfl_xor(rs, 8);
            lrun[r] = lrun[r] * alpha[r] + rs;
        }
        #pragma unroll
        for (int dt = 0; dt < 4; dt++)
            #pragma unroll
            for (int r = 0; r < 4; r++) oacc[dt][r] *= alpha[r];

        // ---- P: C-layout -> A-layout via per-wave LDS (same-wave, no barrier) ----
        #pragma unroll
        for (int nt = 0; nt < 4; nt++)
            #pragma unroll
            for (int r = 0; r < 4; r++)
                Ps[w][kg * 4 + r][nt * 16 + lr] = (f16_t)sv[nt][r];

        __syncthreads();   // all waves done reading K from KVs

        // ---- stage V^T over the same buffer ----
        const long long vrow = (long long)z * 131072 + (long long)sr * 2048 + n0;
        *reinterpret_cast<f16x8*>(&KVs[sr][sc])     = *reinterpret_cast<const f16x8*>(&VT[vrow + sc]);
        *reinterpret_cast<f16x8*>(&KVs[sr][sc + 8]) = *reinterpret_cast<const f16x8*>(&VT[vrow + sc + 8]);
        __syncthreads();

        // ---- PV ----
        f16x8 pa0 = *reinterpret_cast<const f16x8*>(&Ps[w][lr][kg * 8]);
        f16x8 pa1 = *reinterpret_cast<const f16x8*>(&Ps[w][lr][32 + kg * 8]);
        #pragma unroll
        for (int dt = 0; dt < 4; dt++) {
            f16x8 vb0 = *reinterpret_cast<const f16x8*>(&KVs[dt * 16 + lr][kg * 8]);
            f16x8 vb1 = *reinterpret_cast<const f16x8*>(&KVs[dt * 16 + lr][32 + kg * 8]);
            oacc[dt] = __builtin_amdgcn_mfma_f32_16x16x32_f16(pa0, vb0, oacc[dt], 0, 0, 0);
            oacc[dt] = __builtin_amdgcn_mfma_f32_16x16x32_f16(pa1, vb1, oacc[dt], 0, 0, 0);
        }
        __syncthreads();   // all waves done reading V before next K stage
    }

    // ---- write unnormalized partials (f16) + (m,l) ----
    f16_t* op = Opart + (long long)c * 2097152;
    const long long orow0 = (long long)(m0 + w * 16) * 1024 + cbase;
    #pragma unroll
    for (int r = 0; r < 4; r++)
        #pragma unroll
        for (int dt = 0; dt < 4; dt++)
            op[orow0 + (long long)(kg * 4 + r) * 1024 + dt * 16 + lr] = (f16_t)oacc[dt][r];
    if (lr == 0) {
        const int b = z >> 2, h = z & 3;
        #pragma unroll
        for (int r = 0; r < 4; r++) {
            const int tok = (m0 + w * 16 + kg * 4 + r) * 4 + b;
            const long long idx = (long long)(c * 4 + h) * 8192 + tok;
            mlm[idx] = mrun[r];
            mll[idx] = lrun[r];
        }
    }
}

// ================= merge 4 split-KV chunks -> O16 f16 =================
__global__ __launch_bounds__(256) void merge_kernel(
    const f16_t* __restrict__ Opart, const float* __restrict__ mlm,
    const float* __restrict__ mll, f16_t* __restrict__ O16)
{
    const int w = threadIdx.x >> 6, lane = threadIdx.x & 63;
    const int trow = blockIdx.x * 4 + w;
    const int h = lane >> 4;
    float m[4], l[4];
    #pragma unroll
    for (int c = 0; c < 4; c++) {
        m[c] = mlm[(long long)(c * 4 + h) * 8192 + trow];
        l[c] = mll[(long long)(c * 4 + h) * 8192 + trow];
    }
    float M = fmaxf(fmaxf(m[0], m[1]), fmaxf(m[2], m[3]));
    float wv[4], L = 0.f;
    #pragma unroll
    for (int c = 0; c < 4; c++) { wv[c] = __expf(m[c] - M); L += wv[c] * l[c]; }
    const float inv = 1.f / L;
    const long long base = (long long)trow * 256 + lane * 4;
    float acc[4] = {};
    #pragma unroll
    for (int c = 0; c < 4; c++) {
        f16x4v v = *reinterpret_cast<const f16x4v*>(&Opart[(long long)c * 2097152 + base]);
        #pragma unroll
        for (int j = 0; j < 4; j++) acc[j] += wv[c] * (float)v[j];
    }
    f16_t o[4] = { (f16_t)(acc[0] * inv), (f16_t)(acc[1] * inv),
                   (f16_t)(acc[2] * inv), (f16_t)(acc[3] * inv) };
    *reinterpret_cast<ulong1*>(&O16[base]) = *reinterpret_cast<ulong1*>(o);
}

// ================= prep: weight transpose-convert, activation convert =================
__global__ __launch_bounds__(256) void wtrans_kernel(
    const float* __restrict__ in, f16_t* __restrict__ out, int R, int C)
{
    __shared__ float tile[32][33];
    const long long zoff = (long long)blockIdx.z * R * C;
    const int r0 = blockIdx.y * 32, c0 = blockIdx.x * 32;
    const int tx = threadIdx.x & 31, ty = threadIdx.x >> 5;
    #pragma unroll
    for (int i = 0; i < 32; i += 8)
        tile[ty + i][tx] = in[zoff + (long long)(r0 + ty + i) * C + c0 + tx];
    __syncthreads();
    #pragma unroll
    for (int i = 0; i < 32; i += 8)
        out[zoff + (long long)(c0 + ty + i) * R + r0 + tx] = (f16_t)tile[tx][ty + i];
}

// four 256x256 transposes in one dispatch (z selects matrix)
__global__ __launch_bounds__(256) void wtrans4_kernel(
    const float* __restrict__ W0, const float* __restrict__ W1,
    const float* __restrict__ W2, const float* __restrict__ W3,
    f16_t* __restrict__ T0, f16_t* __restrict__ T1,
    f16_t* __restrict__ T2, f16_t* __restrict__ T3)
{
    __shared__ float tile[32][33];
    const int z = blockIdx.z;
    const float* in = (z == 0) ? W0 : (z == 1 ? W1 : (z == 2 ? W2 : W3));
    f16_t* out = (z == 0) ? T0 : (z == 1 ? T1 : (z == 2 ? T2 : T3));
    const int r0 = blockIdx.y * 32, c0 = blockIdx.x * 32;
    const int tx = threadIdx.x & 31, ty = threadIdx.x >> 5;
    #pragma unroll
    for (int i = 0; i < 32; i += 8)
        tile[ty + i][tx] = in[(long long)(r0 + ty + i) * 256 + c0 + tx];
    __syncthreads();
    #pragma unroll
    for (int i = 0; i < 32; i += 8)
        out[(long long)(c0 + ty + i) * 256 + r0 + tx] = (f16_t)tile[tx][ty + i];
}

// both activations converted in one dispatch
__global__ __launch_bounds__(256) void cvt16_kernel(
    const float* __restrict__ a, const float* __restrict__ b,
    f16_t* __restrict__ oa, f16_t* __restrict__ ob)
{
    long long i = ((long long)blockIdx.x * 256 + threadIdx.x) * 4;
    const float* in = a; f16_t* out = oa;
    if (i >= 2097152) { in = b; out = ob; i -= 2097152; }
    float4 v = *reinterpret_cast<const float4*>(&in[i]);
    f16_t o[4] = { (f16_t)v.x, (f16_t)v.y, (f16_t)v.z, (f16_t)v.w };
    *reinterpret_cast<ulong1*>(&out[i]) = *reinterpret_cast<ulong1*>(o);
}

// ================= LN(in1+in2)*g+b -> f32 (+optional f16) =================
__global__ __launch_bounds__(256) void ln_kernel(
    const float* __restrict__ in1, const float* __restrict__ in2,
    const float* __restrict__ gamma, const float* __restrict__ beta,
    float* __restrict__ out, f16_t* __restrict__ out16)
{
    const int wave = threadIdx.x >> 6, lane = threadIdx.x & 63;
    const long long row = (long long)blockIdx.x * 4 + wave;
    const long long base = row * 256 + lane * 4;
    float4 a = *reinterpret_cast<const float4*>(&in1[base]);
    float4 b = *reinterpret_cast<const float4*>(&in2[base]);
    float x[4] = { a.x + b.x, a.y + b.y, a.z + b.z, a.w + b.w };
    float s = x[0] + x[1] + x[2] + x[3];
    float s2 = x[0]*x[0] + x[1]*x[1] + x[2]*x[2] + x[3]*x[3];
    #pragma unroll
    for (int o = 32; o; o >>= 1) { s += __shfl_xor(s, o); s2 += __shfl_xor(s2, o); }
    const float mean = s * (1.f / 256.f);
    const float var = s2 * (1.f / 256.f) - mean * mean;
    const float rstd = rsqrtf(var + 1e-5f);
    float4 g = *reinterpret_cast<const float4*>(&gamma[lane * 4]);
    float4 bb = *reinterpret_cast<const float4*>(&beta[lane * 4]);
    const float* gf = reinterpret_cast<const float*>(&g);
    const float* bf = reinterpret_cast<const float*>(&bb);
    float y[4];
    #pragma unroll
    for (int i = 0; i < 4; i++) y[i] = (x[i] - mean) * rstd * gf[i] + bf[i];
    *reinterpret_cast<float4*>(&out[base]) = make_float4(y[0], y[1], y[2], y[3]);
    if (out16) {
        f16_t o[4] = { (f16_t)y[0], (f16_t)y[1], (f16_t)y[2], (f16_t)y[3] };
        *reinterpret_cast<ulong1*>(&out16[base]) = *reinterpret_cast<ulong1*>(o);
    }
}

// ================= gating (1 thread/token, hierarchical) =================
__global__ __launch_bounds__(256) void gating_kernel(
    const float* __restrict__ X, const float* __restrict__ Wg, const float* __restrict__ bg,
    int* __restrict__ gcount, float* __restrict__ counts,
    int* __restrict__ pos_of_tok, int* __restrict__ exp_of_tok,
    float* __restrict__ gate_of_tok)
{
    __shared__ float WgL[2048];
    __shared__ float cpart[8];
    __shared__ int lcnt[8];
    __shared__ int lbase[8];
    const int t = threadIdx.x;
    for (int i = t; i < 2048; i += 256) WgL[i] = Wg[i];
    if (t < 8) { cpart[t] = 0.f; lcnt[t] = 0; }
    __syncthreads();

    const int tok = blockIdx.x * 256 + t;
    const float* xr = X + (long long)tok * 256;
    float acc[8] = {};
    for (int k = 0; k < 256; k += 4) {
        float4 xv = *reinterpret_cast<const float4*>(xr + k);
        const float* xf = reinterpret_cast<const float*>(&xv);
        #pragma unroll
        for (int i = 0; i < 4; i++) {
            const float xi = xf[i];
            const float* wrow = &WgL[(k + i) * 8];
            #pragma unroll
            for (int e = 0; e < 8; e++) acc[e] += xi * wrow[e];
        }
    }
    float p[8]; float mx = -1e30f;
    #pragma unroll
    for (int e = 0; e < 8; e++) { p[e] = acc[e] + bg[e]; mx = fmaxf(mx, p[e]); }
    float se = 0.f;
    #pragma unroll
    for (int e = 0; e < 8; e++) { p[e] = __expf(p[e] - mx); se += p[e]; }
    const float inv = 1.f / se;
    #pragma unroll
    for (int e = 0; e < 8; e++) { p[e] *= inv; atomicAdd(&cpart[e], p[e]); }

    int i1 = 0;
    #pragma unroll
    for (int e = 1; e < 8; e++) if (p[e] > p[i1]) i1 = e;
    int i2 = (i1 == 0) ? 1 : 0;
    #pragma unroll
    for (int e = 0; e < 8; e++) if (e != i1 && p[e] > p[i2]) i2 = e;
    const float gs = 1.f / (p[i1] + p[i2]);

    const int p1 = atomicAdd(&lcnt[i1], 1);
    const int p2 = atomicAdd(&lcnt[i2], 1);
    __syncthreads();
    if (t < 8) {
        lbase[t] = atomicAdd(&gcount[t], lcnt[t]);
        atomicAdd(&counts[t], cpart[t]);
    }
    __syncthreads();
    pos_of_tok[2 * tok]     = lbase[i1] + p1;
    pos_of_tok[2 * tok + 1] = lbase[i2] + p2;
    exp_of_tok[2 * tok]     = i1;
    exp_of_tok[2 * tok + 1] = i2;
    gate_of_tok[2 * tok]     = p[i1] * gs;
    gate_of_tok[2 * tok + 1] = p[i2] * gs;
}

__global__ void finalize_kernel(const int* __restrict__ gcount, int* __restrict__ ebase)
{
    if (threadIdx.x == 0) {
        int b = 0;
        for (int e = 0; e < 8; e++) { ebase[e] = b; b += (gcount[e] + 63) & ~63; }
        ebase[8] = b;
    }
}

__global__ __launch_bounds__(256) void scatter_kernel(
    const int* __restrict__ pos_of_tok, const int* __restrict__ exp_of_tok,
    const int* __restrict__ ebase, int* __restrict__ tok_of_slot)
{
    const int i = blockIdx.x * 256 + threadIdx.x;
    const int e = exp_of_tok[i];
    tok_of_slot[ebase[e] + pos_of_tok[i]] = i >> 1;
}

// out = LN(gv1*Ys[s1] + gv2*Ys[s2] + X1), optional f16 copy
__global__ __launch_bounds__(256) void moe_combine_ln_kernel(
    const float* __restrict__ Ys, const float* __restrict__ X1,
    const int* __restrict__ pos_of_tok, const int* __restrict__ exp_of_tok,
    const float* __restrict__ gate_of_tok, const int* __restrict__ ebase,
    const float* __restrict__ gamma, const float* __restrict__ beta,
    float* __restrict__ out, f16_t* __restrict__ out16)
{
    const int wave = threadIdx.x >> 6, lane = threadIdx.x & 63;
    const long long tok = (long long)blockIdx.x * 4 + wave;
    const int e1 = exp_of_tok[2 * tok], e2 = exp_of_tok[2 * tok + 1];
    const long long s1 = ebase[e1] + pos_of_tok[2 * tok];
    const long long s2 = ebase[e2] + pos_of_tok[2 * tok + 1];
    const float gv1 = gate_of_tok[2 * tok], gv2 = gate_of_tok[2 * tok + 1];
    const long long base = tok * 256 + lane * 4;
    float4 y1 = *reinterpret_cast<const float4*>(&Ys[s1 * 256 + lane * 4]);
    float4 y2 = *reinterpret_cast<const float4*>(&Ys[s2 * 256 + lane * 4]);
    float4 xv = *reinterpret_cast<const float4*>(&X1[base]);
    float x[4] = { gv1 * y1.x + gv2 * y2.x + xv.x,
                   gv1 * y1.y + gv2 * y2.y + xv.y,
                   gv1 * y1.z + gv2 * y2.z + xv.z,
                   gv1 * y1.w + gv2 * y2.w + xv.w };
    float s = x[0] + x[1] + x[2] + x[3];
    float s2v = x[0]*x[0] + x[1]*x[1] + x[2]*x[2] + x[3]*x[3];
    #pragma unroll
    for (int o = 32; o; o >>= 1) { s += __shfl_xor(s, o); s2v += __shfl_xor(s2v, o); }
    const float mean = s * (1.f / 256.f);
    const float var = s2v * (1.f / 256.f) - mean * mean;
    const float rstd = rsqrtf(var + 1e-5f);
    float4 g = *reinterpret_cast<const float4*>(&gamma[lane * 4]);
    float4 bb = *reinterpret_cast<const float4*>(&beta[lane * 4]);
    const float* gf = reinterpret_cast<const float*>(&g);
    const float* bf = reinterpret_cast<const float*>(&bb);
    float y[4];
    #pragma unroll
    for (int i = 0; i < 4; i++) y[i] = (x[i] - mean) * rstd * gf[i] + bf[i];
    *reinterpret_cast<float4*>(&out[base]) = make_float4(y[0], y[1], y[2], y[3]);
    if (out16) {
        f16_t o[4] = { (f16_t)y[0], (f16_t)y[1], (f16_t)y[2], (f16_t)y[3] };
        *reinterpret_cast<ulong1*>(&out16[base]) = *reinterpret_cast<ulong1*>(o);
    }
}

__global__ void aux_kernel(const float* __restrict__ counts, float* __restrict__ out)
{
    if (threadIdx.x == 0) {
        float aux = 0.f;
        for (int pzz = 0; pzz < 2; pzz++) {
            const float* c = counts + pzz * 8;
            float tot = 0.f;
            for (int e = 0; e < 8; e++) tot += c[e];
            float s = 0.f;
            for (int e = 0; e < 8; e++) s += (c[e] / tot) * (c[e] * (1.f / 8192.f));
            aux += 8.f * s;
        }
        out[0] = 0.01f * aux;
    }
}

extern "C" void kernel_launch(void* const* d_in, const int* in_sizes, int n_in,
                              void* d_out, int out_size, void* d_ws, size_t ws_size,
                              hipStream_t stream)
{
    const float* Xc  = (const float*)d_in[0];
    const float* Xt  = (const float*)d_in[1];
    const float* Wq  = (const float*)d_in[2];
    const float* Wk  = (const float*)d_in[3];
    const float* Wv  = (const float*)d_in[4];
    const float* bq  = (const float*)d_in[5];
    const float* bk  = (const float*)d_in[6];
    const float* bv  = (const float*)d_in[7];
    const float* Wo  = (const float*)d_in[8];
    const float* bo  = (const float*)d_in[9];
    const float* Wg  = (const float*)d_in[10];
    const float* bg  = (const float*)d_in[11];
    const float* W1  = (const float*)d_in[12];
    const float* b1  = (const float*)d_in[13];
    const float* W2  = (const float*)d_in[14];
    const float* b2  = (const float*)d_in[15];
    const float* g_c1 = (const float*)d_in[16];
    const float* b_c1 = (const float*)d_in[17];
    const float* g_c2 = (const float*)d_in[18];
    const float* b_c2 = (const float*)d_in[19];
    const float* g_t1 = (const float*)d_in[20];
    const float* b_t1 = (const float*)d_in[21];
    const float* g_t2 = (const float*)d_in[22];
    const float* b_t2 = (const float*)d_in[23];

    const long long NTOK = 2097152;          // 8192 tokens * 256
    const int SLOT_MAX = 16896;              // 264 * 64
    float* dout = (float*)d_out;             // fp32: xc | xt | aux
    float* xcout = dout;
    float* xtout = dout + NTOK;

    float* ws = (float*)d_ws;
    float* P1 = ws;
    float* X1 = P1 + NTOK;
    float* Ys = X1 + NTOK;                               // SLOT_MAX x 256
    float* counts      = Ys + (long long)SLOT_MAX * 256; // 16 f32
    int*   gcount      = (int*)(counts + 16);            // 16 i32 (adjacent: one memset)
    float* gate_of_tok = (float*)(gcount + 16);          // 16384
    float* mlm = gate_of_tok + 16384;                    // 4*4*8192
    float* mll = mlm + 131072;                           // 4*4*8192
    int* ebase       = (int*)(mll + 131072);             // 16
    int* pos_of_tok  = ebase + 16;                       // 16384
    int* exp_of_tok  = pos_of_tok + 16384;               // 16384
    int* tok_of_slot = exp_of_tok + 16384;               // SLOT_MAX
    f16_t* h16 = (f16_t*)(tok_of_slot + SLOT_MAX);
    f16_t* Xc16 = h16;
    f16_t* Xt16 = Xc16 + NTOK;
    f16_t* xc16 = Xt16 + NTOK;
    f16_t* Q16  = xc16 + NTOK;
    f16_t* K16  = Q16 + NTOK;
    f16_t* V16  = K16 + NTOK;
    f16_t* O16  = V16 + NTOK;
    f16_t* X116 = O16 + NTOK;
    f16_t* VT   = X116 + NTOK;                           // 16 z x 64 d x 2048 s
    f16_t* Hs16 = VT + NTOK;                             // SLOT_MAX x 1024 (MoE phase)
    f16_t* WqT  = Hs16 + (long long)SLOT_MAX * 1024;
    f16_t* WkT  = WqT + 65536;
    f16_t* WvT  = WkT + 65536;
    f16_t* WoT  = WvT + 65536;
    f16_t* W1T  = WoT + 65536;                           // 8 x 1024 x 256
    f16_t* W2T  = W1T + 2097152;                         // 8 x 256 x 1024
    f16_t* Opart = Hs16;                                 // alias: attention phase only (4*NTOK f16 = 16MB)

    hipMemsetAsync(counts, 0, 32 * sizeof(int), stream);   // counts(16f) + gcount(16i)

    // ---- prep ----
    cvt16_kernel<<<4096, 256, 0, stream>>>(Xc, Xt, Xc16, Xt16);
    wtrans4_kernel<<<dim3(8, 8, 4), 256, 0, stream>>>(Wq, Wk, Wv, Wo, WqT, WkT, WvT, WoT);
    wtrans_kernel<<<dim3(32, 8, 8), 256, 0, stream>>>(W1, W1T, 256, 1024);
    wtrans_kernel<<<dim3(8, 32, 8), 256, 0, stream>>>(W2, W2T, 1024, 256);

    for (int pass = 0; pass < 2; pass++) {
        const float*  xq    = pass ? Xt   : Xc;
        const f16_t*  xq16  = pass ? Xt16 : Xc16;
        const f16_t*  xkv16 = pass ? xc16 : Xc16;
        const float* g1  = pass ? g_t1 : g_c1;
        const float* be1 = pass ? b_t1 : b_c1;
        const float* g2  = pass ? g_t2 : g_c2;
        const float* be2 = pass ? b_t2 : b_c2;
        float* cnt = counts + pass * 8;
        int* gcnt  = gcount + pass * 8;
        float* oln = pass ? xtout : xcout;
        f16_t* oln16 = pass ? nullptr : xc16;

        // Q/K/V projections in one dispatch
        qkv_kernel<<<dim3(4, 128, 3), 256, 0, stream>>>(
            xq16, xkv16, WqT, WkT, WvT, bq, bk, bv, Q16, K16, V16);

        // V -> VT[z][d][s], then split-KV flash + merge
        vtrans_kernel<<<dim3(64, 2, 16), 256, 0, stream>>>(V16, VT);
        flash_kernel<<<dim3(32, 16, 4), 256, 0, stream>>>(Q16, K16, VT, Opart, mlm, mll);
        merge_kernel<<<2048, 256, 0, stream>>>(Opart, mlm, mll, O16);

        // output projection + LN1 (dual f32/f16)
        gemm16_kernel<true,false><<<dim3(4, 128), 256, 0, stream>>>(
            O16, WoT, P1, bo, 8192, 256, 256, 256, 256, 256);
        ln_kernel<<<2048, 256, 0, stream>>>(P1, xq, g1, be1, X1, X116);

        // ---- sparse top-2 MoE ----
        gating_kernel<<<32, 256, 0, stream>>>(X1, Wg, bg, gcnt, cnt,
                                              pos_of_tok, exp_of_tok, gate_of_tok);
        finalize_kernel<<<1, 64, 0, stream>>>(gcnt, ebase);
        scatter_kernel<<<64, 256, 0, stream>>>(pos_of_tok, exp_of_tok, ebase, tok_of_slot);
        moe_gemm16_kernel<true,true,true><<<dim3(16, 264), 256, 0, stream>>>(
            X116, tok_of_slot, W1T, b1, Hs16, ebase,
            1024, 256, 256, 256, 1024, 262144, 1024);
        moe_gemm16_kernel<false,false,false><<<dim3(4, 264), 256, 0, stream>>>(
            Hs16, nullptr, W2T, b2, Ys, ebase,
            256, 1024, 1024, 1024, 256, 262144, 256);
        moe_combine_ln_kernel<<<2048, 256, 0, stream>>>(
            Ys, X1, pos_of_tok, exp_of_tok, gate_of_tok, ebase, g2, be2, oln, oln16);
    }

    aux_kernel<<<1, 64, 0, stream>>>(counts, dout + 2 * NTOK);
}